// Round 14
// baseline (128.767 us; speedup 1.0000x reference)
//
#include <hip/hip_runtime.h>
#include <math.h>

#define Bv  4
#define Cv  64
#define DCv 32
#define Fv  128
#define Tv  512
#define FT  (Fv * 512)

// ---------------------------------------------------------------------------
// KPREP: fold BN into weights and TRANSPOSE for k-major access.
// W1T[k][c] = w1[c][k]*s1[c]  (64x32)   B1f[c]
// W2T[k][o] = wp[o][k]*s2[o]  (32x64)   B2f[o]
// ---------------------------------------------------------------------------
__global__ __launch_bounds__(512)
void kprep(const float* __restrict__ w1, const float* __restrict__ b1,
           const float* __restrict__ g1, const float* __restrict__ be1,
           const float* __restrict__ m1, const float* __restrict__ v1,
           const float* __restrict__ wp, const float* __restrict__ bp,
           const float* __restrict__ g2, const float* __restrict__ be2,
           const float* __restrict__ m2, const float* __restrict__ v2,
           float* __restrict__ W1T, float* __restrict__ B1f,
           float* __restrict__ W2T, float* __restrict__ B2f)
{
    const int tid = threadIdx.x;
    #pragma unroll
    for (int i = 0; i < 4; ++i) {
        const int e = tid * 4 + i;          // W1T: e = k*32 + c
        const int c = e & 31, k = e >> 5;
        W1T[e] = w1[c * Cv + k] * (g1[c] * rsqrtf(v1[c] + 1e-5f));
    }
    #pragma unroll
    for (int i = 0; i < 4; ++i) {
        const int e = tid * 4 + i;          // W2T: e = k*64 + o
        const int o = e & 63, k = e >> 6;
        W2T[e] = wp[o * DCv + k] * (g2[o] * rsqrtf(v2[o] + 1e-5f));
    }
    if (tid < DCv) {
        const float s = g1[tid] * rsqrtf(v1[tid] + 1e-5f);
        B1f[tid] = (b1[tid] - m1[tid]) * s + be1[tid];
    }
    if (tid < Cv) {
        const float s = g2[tid] * rsqrtf(v2[tid] + 1e-5f);
        B2f[tid] = (bp[tid] - m2[tid]) * s + be2[tid];
    }
}

// ---------------------------------------------------------------------------
// KC1: conv1, streaming (NO X staging). grid (bf,half)=1024 x 256 (4 waves).
// Wave w: rows w*8..+7; lane: 4 t. Per k: 1 coalesced global b128 (X) +
// 2 LDS b128 (W1T, pre-staged once) + 32 FMA. X read x4-redundant -> L2.
// ~55 VGPR, 8.2 KB LDS, 1 barrier -> 8 blocks/CU.
// ---------------------------------------------------------------------------
#define KC1_ROW(ar, r) \
    acc[(r)*4+0] = fmaf(ar, x.x, acc[(r)*4+0]); \
    acc[(r)*4+1] = fmaf(ar, x.y, acc[(r)*4+1]); \
    acc[(r)*4+2] = fmaf(ar, x.z, acc[(r)*4+2]); \
    acc[(r)*4+3] = fmaf(ar, x.w, acc[(r)*4+3]);

__global__ __launch_bounds__(256, 8)
void kc1_conv(const float* __restrict__ inp,
              const float* __restrict__ W1T, const float* __restrict__ B1f,
              const float* __restrict__ a1,
              float* __restrict__ Qws)
{
    __shared__ __align__(16) float sW[Cv * DCv];   // 8 KB [k][c]
    __shared__ float sB[DCv];

    const int tid  = threadIdx.x;
    const int bid  = blockIdx.x;
    const int half = bid & 1;
    const int bf   = bid >> 1;
    const int b    = bf >> 7;
    const int f    = bf & 127;

    {
        const int e = tid * 8;
        *(float4*)&sW[e]     = *(const float4*)&W1T[e];
        *(float4*)&sW[e + 4] = *(const float4*)&W1T[e + 4];
    }
    if (tid < DCv) sB[tid] = B1f[tid];
    const float alpha1 = a1[0];
    __syncthreads();

    const int w  = tid >> 6, l = tid & 63;
    const int r0 = w * 8;
    const float* px = inp + (size_t)(b * Cv) * FT + f * 512 + half * 256 + l * 4;

    float acc[32];
    #pragma unroll
    for (int i = 0; i < 32; ++i) acc[i] = 0.f;

    #pragma unroll 8
    for (int k = 0; k < Cv; ++k) {
        const float4 x   = *(const float4*)&px[(size_t)k * FT];
        const float4 a0  = *(const float4*)&sW[k * DCv + r0];
        const float4 a1v = *(const float4*)&sW[k * DCv + r0 + 4];
        KC1_ROW(a0.x, 0) KC1_ROW(a0.y, 1) KC1_ROW(a0.z, 2) KC1_ROW(a0.w, 3)
        KC1_ROW(a1v.x, 4) KC1_ROW(a1v.y, 5) KC1_ROW(a1v.z, 6) KC1_ROW(a1v.w, 7)
    }

    const float b0 = sB[r0+0], b1_ = sB[r0+1], b2 = sB[r0+2], b3 = sB[r0+3];
    const float b4 = sB[r0+4], b5  = sB[r0+5], b6 = sB[r0+6], b7 = sB[r0+7];
    float* qg = Qws + ((size_t)bf * Tv + half * 256 + l * 4) * DCv + r0;
    #pragma unroll
    for (int j = 0; j < 4; ++j) {
        float z0 = acc[0*4+j] + b0, z1 = acc[1*4+j] + b1_;
        float z2 = acc[2*4+j] + b2, z3 = acc[3*4+j] + b3;
        float z4 = acc[4*4+j] + b4, z5 = acc[5*4+j] + b5;
        float z6 = acc[6*4+j] + b6, z7 = acc[7*4+j] + b7;
        z0 = z0 >= 0.f ? z0 : alpha1 * z0;  z1 = z1 >= 0.f ? z1 : alpha1 * z1;
        z2 = z2 >= 0.f ? z2 : alpha1 * z2;  z3 = z3 >= 0.f ? z3 : alpha1 * z3;
        z4 = z4 >= 0.f ? z4 : alpha1 * z4;  z5 = z5 >= 0.f ? z5 : alpha1 * z5;
        z6 = z6 >= 0.f ? z6 : alpha1 * z6;  z7 = z7 >= 0.f ? z7 : alpha1 * z7;
        float4 v0; v0.x = z0; v0.y = z1; v0.z = z2; v0.w = z3;
        float4 v1; v1.x = z4; v1.y = z5; v1.z = z6; v1.w = z7;
        *(float4*)&qg[j * DCv]     = v0;
        *(float4*)&qg[j * DCv + 4] = v1;
    }
}

// ---------------------------------------------------------------------------
// KM: M = Q Q^T / sqrt(32). One block per bf. Proven (~8-10 us).
// ---------------------------------------------------------------------------
__global__ __launch_bounds__(256)
void km_build(const float* __restrict__ Qws, float* __restrict__ Mfull)
{
    __shared__ __align__(16) float sP[4][1024];  // 16 KB

    const int tid   = threadIdx.x;
    const int bf    = blockIdx.x;
    const int slice = tid >> 6;
    const int l     = tid & 63;
    const int c1b   = l >> 3;
    const int c2b   = l & 7;

    const float* qp = Qws + ((size_t)bf * Tv + slice * 128) * DCv;
    float4 r0 = {0,0,0,0}, r1 = {0,0,0,0}, r2 = {0,0,0,0}, r3 = {0,0,0,0};
    #pragma unroll 4
    for (int i = 0; i < 128; ++i) {
        const float4 qa = *(const float4*)&qp[i * 32 + c1b * 4];
        const float4 qb = *(const float4*)&qp[i * 32 + c2b * 4];
        r0.x = fmaf(qa.x, qb.x, r0.x); r0.y = fmaf(qa.x, qb.y, r0.y);
        r0.z = fmaf(qa.x, qb.z, r0.z); r0.w = fmaf(qa.x, qb.w, r0.w);
        r1.x = fmaf(qa.y, qb.x, r1.x); r1.y = fmaf(qa.y, qb.y, r1.y);
        r1.z = fmaf(qa.y, qb.z, r1.z); r1.w = fmaf(qa.y, qb.w, r1.w);
        r2.x = fmaf(qa.z, qb.x, r2.x); r2.y = fmaf(qa.z, qb.y, r2.y);
        r2.z = fmaf(qa.z, qb.z, r2.z); r2.w = fmaf(qa.z, qb.w, r2.w);
        r3.x = fmaf(qa.w, qb.x, r3.x); r3.y = fmaf(qa.w, qb.y, r3.y);
        r3.z = fmaf(qa.w, qb.z, r3.z); r3.w = fmaf(qa.w, qb.w, r3.w);
    }
    *(float4*)&sP[slice][(c1b * 4 + 0) * DCv + c2b * 4] = r0;
    *(float4*)&sP[slice][(c1b * 4 + 1) * DCv + c2b * 4] = r1;
    *(float4*)&sP[slice][(c1b * 4 + 2) * DCv + c2b * 4] = r2;
    *(float4*)&sP[slice][(c1b * 4 + 3) * DCv + c2b * 4] = r3;
    __syncthreads();

    const float INV = 0.17677669529663687f;  // 1/sqrt(32)
    float4 v0 = *(const float4*)&sP[0][tid * 4];
    float4 v1 = *(const float4*)&sP[1][tid * 4];
    float4 v2 = *(const float4*)&sP[2][tid * 4];
    float4 v3 = *(const float4*)&sP[3][tid * 4];
    float4 o;
    o.x = ((v0.x + v1.x) + (v2.x + v3.x)) * INV;
    o.y = ((v0.y + v1.y) + (v2.y + v3.y)) * INV;
    o.z = ((v0.z + v1.z) + (v2.z + v3.z)) * INV;
    o.w = ((v0.w + v1.w) + (v2.w + v3.w)) * INV;
    *(float4*)&Mfull[(size_t)bf * 1024 + tid * 4] = o;
}

// ---------------------------------------------------------------------------
// KA: O = M*Q per (bf, t-quarter). grid 2048 x 256 (4 waves). M (symmetric,
// so [k][r] access == [r][k], no transpose) 4 KB LDS; Q quarter 16 KB LDS.
// Wave: 8 rows x 128 t (lane = 2 t). Chunk softmax stats (max, sum) -> global;
// RAW O written IN PLACE over the Q quarter ([t][c], block-local region).
// ---------------------------------------------------------------------------
#define KA_ROW(ar, r) \
    acc[(r)*2+0] = fmaf(ar, x.x, acc[(r)*2+0]); \
    acc[(r)*2+1] = fmaf(ar, x.y, acc[(r)*2+1]);

__global__ __launch_bounds__(256, 8)
void ka_scores(float* __restrict__ Qio, const float* __restrict__ Mfull,
               float* __restrict__ Smx, float* __restrict__ Ssum)
{
    __shared__ __align__(16) float sM[DCv * DCv];   // 4 KB
    __shared__ __align__(16) float sQ[DCv * 128];   // 16 KB [k][t]

    const int tid = threadIdx.x;
    const int bid = blockIdx.x;
    const int q   = bid & 3;
    const int bf  = bid >> 2;
    const int f   = bf & 127;

    *(float4*)&sM[tid * 4] = *(const float4*)&Mfull[(size_t)bf * 1024 + tid * 4];

    const int tloc = tid >> 1, c0 = (tid & 1) * 16;
    float* qg = Qio + ((size_t)bf * Tv + q * 128 + tloc) * DCv + c0;
    {
        float4 A = *(const float4*)&qg[0];
        float4 B = *(const float4*)&qg[4];
        float4 C = *(const float4*)&qg[8];
        float4 D = *(const float4*)&qg[12];
        sQ[(c0+ 0)*128+tloc]=A.x; sQ[(c0+ 1)*128+tloc]=A.y; sQ[(c0+ 2)*128+tloc]=A.z; sQ[(c0+ 3)*128+tloc]=A.w;
        sQ[(c0+ 4)*128+tloc]=B.x; sQ[(c0+ 5)*128+tloc]=B.y; sQ[(c0+ 6)*128+tloc]=B.z; sQ[(c0+ 7)*128+tloc]=B.w;
        sQ[(c0+ 8)*128+tloc]=C.x; sQ[(c0+ 9)*128+tloc]=C.y; sQ[(c0+10)*128+tloc]=C.z; sQ[(c0+11)*128+tloc]=C.w;
        sQ[(c0+12)*128+tloc]=D.x; sQ[(c0+13)*128+tloc]=D.y; sQ[(c0+14)*128+tloc]=D.z; sQ[(c0+15)*128+tloc]=D.w;
    }
    __syncthreads();

    const int w = tid >> 6, l = tid & 63;
    const int r0 = w * 8, tt = l * 2;
    const int limit = f + (Tv - Fv + 1);

    float acc[16];
    #pragma unroll
    for (int i = 0; i < 16; ++i) acc[i] = 0.f;

    #pragma unroll 8
    for (int k = 0; k < DCv; ++k) {
        const float4 a0  = *(const float4*)&sM[k * DCv + r0];
        const float4 a1v = *(const float4*)&sM[k * DCv + r0 + 4];
        const float2 x   = *(const float2*)&sQ[k * 128 + tt];
        KA_ROW(a0.x, 0) KA_ROW(a0.y, 1) KA_ROW(a0.z, 2) KA_ROW(a0.w, 3)
        KA_ROW(a1v.x, 4) KA_ROW(a1v.y, 5) KA_ROW(a1v.z, 6) KA_ROW(a1v.w, 7)
    }

    // mask (only quarter 3 can be masked: limit >= 385); branch-free fill
    bool v0 = true, v1 = true;
    if (q == 3) {
        const int tg = 384 + tt;
        v0 = tg < limit;
        v1 = tg + 1 < limit;
        #pragma unroll
        for (int r = 0; r < 8; ++r) {
            acc[r*2+0] = v0 ? acc[r*2+0] : -INFINITY;
            acc[r*2+1] = v1 ? acc[r*2+1] : -INFINITY;
        }
    }

    // per-row chunk stats (row fully within this wave)
    #pragma unroll
    for (int r = 0; r < 8; ++r) {
        float mx = fmaxf(acc[r*2], acc[r*2+1]);
        #pragma unroll
        for (int s = 1; s < 64; s <<= 1) mx = fmaxf(mx, __shfl_xor(mx, s));
        float e0 = v0 ? __expf(acc[r*2]   - mx) : 0.f;
        float e1 = v1 ? __expf(acc[r*2+1] - mx) : 0.f;
        float sum = e0 + e1;
        #pragma unroll
        for (int s = 1; s < 64; s <<= 1) sum += __shfl_xor(sum, s);
        if (l == 0) {
            Smx [((size_t)bf * DCv + r0 + r) * 4 + q] = mx;
            Ssum[((size_t)bf * DCv + r0 + r) * 4 + q] = sum;
        }
    }

    // store RAW O in place over the Q quarter ([t][c])
    float* og = Qio + ((size_t)bf * Tv + q * 128 + tt) * DCv + r0;
    float4 s00; s00.x = acc[0];  s00.y = acc[2];  s00.z = acc[4];  s00.w = acc[6];
    float4 s01; s01.x = acc[8];  s01.y = acc[10]; s01.z = acc[12]; s01.w = acc[14];
    float4 s10; s10.x = acc[1];  s10.y = acc[3];  s10.z = acc[5];  s10.w = acc[7];
    float4 s11; s11.x = acc[9];  s11.y = acc[11]; s11.z = acc[13]; s11.w = acc[15];
    *(float4*)&og[0]       = s00; *(float4*)&og[4]       = s01;
    *(float4*)&og[DCv]     = s10; *(float4*)&og[DCv + 4] = s11;
}

// ---------------------------------------------------------------------------
// KB: combine stats -> P -> conv2-GEMM (W2T in LDS) -> PReLU -> +residual.
// grid 2048 x 256 per (bf, t-quarter). Wave: 16 oc-rows x 128 t (lane 2 t).
// Epilogue in 4-row batches to cap VGPR (~70). 25 KB LDS -> 6 blocks/CU.
// ---------------------------------------------------------------------------
__global__ __launch_bounds__(256, 6)
void kb_out(const float* __restrict__ inp, const float* __restrict__ Ows,
            const float* __restrict__ Smx, const float* __restrict__ Ssum,
            const float* __restrict__ W2T, const float* __restrict__ B2f,
            const float* __restrict__ a2,
            float* __restrict__ out)
{
    __shared__ __align__(16) float sW[DCv * Cv];    // 8 KB [k][oc]
    __shared__ __align__(16) float sP[DCv * 128];   // 16 KB [k][t]
    __shared__ float sMx[DCv], sRZ[DCv], sB[Cv];

    const int tid = threadIdx.x;
    const int bid = blockIdx.x;
    const int q   = bid & 3;
    const int bf  = bid >> 2;
    const int b   = bf >> 7;
    const int f   = bf & 127;

    {
        const int e = tid * 8;
        *(float4*)&sW[e]     = *(const float4*)&W2T[e];
        *(float4*)&sW[e + 4] = *(const float4*)&W2T[e + 4];
    }
    if (tid < Cv) sB[tid] = B2f[tid];
    if (tid < DCv) {
        float4 mv = *(const float4*)&Smx [((size_t)bf * DCv + tid) * 4];
        float4 sv = *(const float4*)&Ssum[((size_t)bf * DCv + tid) * 4];
        float gm = fmaxf(fmaxf(mv.x, mv.y), fmaxf(mv.z, mv.w));
        float Z = sv.x * __expf(mv.x - gm) + sv.y * __expf(mv.y - gm)
                + sv.z * __expf(mv.z - gm) + sv.w * __expf(mv.w - gm);
        sMx[tid] = gm;
        sRZ[tid] = 1.f / Z;
    }
    const float alpha2 = a2[0];
    __syncthreads();

    // P stage: read O quarter ([t][c]) -> normalize -> sP[k][t]
    {
        const int tloc = tid >> 1, c0 = (tid & 1) * 16;
        const float* og = Ows + ((size_t)bf * Tv + q * 128 + tloc) * DCv + c0;
        float4 A = *(const float4*)&og[0];
        float4 B = *(const float4*)&og[4];
        float4 C = *(const float4*)&og[8];
        float4 D = *(const float4*)&og[12];
        const float* mxp = &sMx[c0];
        const float* rzp = &sRZ[c0];
        sP[(c0+ 0)*128+tloc] = __expf(A.x - mxp[ 0]) * rzp[ 0];
        sP[(c0+ 1)*128+tloc] = __expf(A.y - mxp[ 1]) * rzp[ 1];
        sP[(c0+ 2)*128+tloc] = __expf(A.z - mxp[ 2]) * rzp[ 2];
        sP[(c0+ 3)*128+tloc] = __expf(A.w - mxp[ 3]) * rzp[ 3];
        sP[(c0+ 4)*128+tloc] = __expf(B.x - mxp[ 4]) * rzp[ 4];
        sP[(c0+ 5)*128+tloc] = __expf(B.y - mxp[ 5]) * rzp[ 5];
        sP[(c0+ 6)*128+tloc] = __expf(B.z - mxp[ 6]) * rzp[ 6];
        sP[(c0+ 7)*128+tloc] = __expf(B.w - mxp[ 7]) * rzp[ 7];
        sP[(c0+ 8)*128+tloc] = __expf(C.x - mxp[ 8]) * rzp[ 8];
        sP[(c0+ 9)*128+tloc] = __expf(C.y - mxp[ 9]) * rzp[ 9];
        sP[(c0+10)*128+tloc] = __expf(C.z - mxp[10]) * rzp[10];
        sP[(c0+11)*128+tloc] = __expf(C.w - mxp[11]) * rzp[11];
        sP[(c0+12)*128+tloc] = __expf(D.x - mxp[12]) * rzp[12];
        sP[(c0+13)*128+tloc] = __expf(D.y - mxp[13]) * rzp[13];
        sP[(c0+14)*128+tloc] = __expf(D.z - mxp[14]) * rzp[14];
        sP[(c0+15)*128+tloc] = __expf(D.w - mxp[15]) * rzp[15];
    }
    __syncthreads();

    const int w = tid >> 6, l = tid & 63;
    const int oc0 = w * 16, tt = l * 2;

    float acc[32];
    #pragma unroll
    for (int i = 0; i < 32; ++i) acc[i] = 0.f;

    #pragma unroll 8
    for (int k = 0; k < DCv; ++k) {
        const float4 a0 = *(const float4*)&sW[k * Cv + oc0];
        const float4 a1 = *(const float4*)&sW[k * Cv + oc0 + 4];
        const float4 a2v= *(const float4*)&sW[k * Cv + oc0 + 8];
        const float4 a3 = *(const float4*)&sW[k * Cv + oc0 + 12];
        const float2 x  = *(const float2*)&sP[k * 128 + tt];
        KA_ROW(a0.x,  0) KA_ROW(a0.y,  1) KA_ROW(a0.z,  2) KA_ROW(a0.w,  3)
        KA_ROW(a1.x,  4) KA_ROW(a1.y,  5) KA_ROW(a1.z,  6) KA_ROW(a1.w,  7)
        KA_ROW(a2v.x, 8) KA_ROW(a2v.y, 9) KA_ROW(a2v.z,10) KA_ROW(a2v.w,11)
        KA_ROW(a3.x, 12) KA_ROW(a3.y, 13) KA_ROW(a3.z, 14) KA_ROW(a3.w, 15)
    }

    const float* rip = inp + (size_t)(b * Cv) * FT + f * 512 + q * 128 + tt;
    float*       pot = out + (size_t)(b * Cv) * FT + f * 512 + q * 128 + tt;
    #pragma unroll
    for (int p = 0; p < 4; ++p) {
        float2 rin0 = *(const float2*)&rip[(size_t)(oc0 + p*4 + 0) * FT];
        float2 rin1 = *(const float2*)&rip[(size_t)(oc0 + p*4 + 1) * FT];
        float2 rin2 = *(const float2*)&rip[(size_t)(oc0 + p*4 + 2) * FT];
        float2 rin3 = *(const float2*)&rip[(size_t)(oc0 + p*4 + 3) * FT];
        #define KB_EPI(rr, RV) {                                              \
            const int oc = oc0 + p*4 + (rr);                                  \
            const float bb = sB[oc];                                          \
            float z0 = acc[(p*4+(rr))*2+0] + bb;                              \
            float z1 = acc[(p*4+(rr))*2+1] + bb;                              \
            z0 = z0 >= 0.f ? z0 : alpha2 * z0;                                \
            z1 = z1 >= 0.f ? z1 : alpha2 * z1;                                \
            float2 ov; ov.x = z0 + RV.x; ov.y = z1 + RV.y;                    \
            *(float2*)&pot[(size_t)oc * FT] = ov; }
        KB_EPI(0, rin0) KB_EPI(1, rin1) KB_EPI(2, rin2) KB_EPI(3, rin3)
        #undef KB_EPI
    }
}

extern "C" void kernel_launch(void* const* d_in, const int* in_sizes, int n_in,
                              void* d_out, int out_size, void* d_ws, size_t ws_size,
                              hipStream_t stream) {
    const float* inp = (const float*)d_in[0];
    const float* w1  = (const float*)d_in[1];
    const float* b1  = (const float*)d_in[2];
    const float* g1  = (const float*)d_in[3];
    const float* be1 = (const float*)d_in[4];
    const float* m1  = (const float*)d_in[5];
    const float* v1  = (const float*)d_in[6];
    const float* a1  = (const float*)d_in[7];
    const float* wp  = (const float*)d_in[8];
    const float* bp  = (const float*)d_in[9];
    const float* g2  = (const float*)d_in[10];
    const float* be2 = (const float*)d_in[11];
    const float* m2  = (const float*)d_in[12];
    const float* v2  = (const float*)d_in[13];
    const float* a2  = (const float*)d_in[14];

    float* Qws   = (float*)d_ws;                            // 8,388,608 f (Q, then O in place)
    float* Mfull = Qws   + (size_t)Bv * Fv * Tv * DCv;      //   524,288 f
    float* Smx   = Mfull + (size_t)512 * 1024;              //    65,536 f
    float* Ssum  = Smx   + (size_t)512 * 128;               //    65,536 f
    float* W1T   = Ssum  + (size_t)512 * 128;               //     2,048 f
    float* B1f   = W1T   + 2048;                            //        32 f
    float* W2T   = B1f   + 32;                              //     2,048 f
    float* B2f   = W2T   + 2048;                            //        64 f

    kprep<<<dim3(1), dim3(512), 0, stream>>>(
        w1, b1, g1, be1, m1, v1, wp, bp, g2, be2, m2, v2, W1T, B1f, W2T, B2f);
    kc1_conv<<<dim3(Bv * Fv * 2), dim3(256), 0, stream>>>(inp, W1T, B1f, a1, Qws);
    km_build<<<dim3(Bv * Fv), dim3(256), 0, stream>>>(Qws, Mfull);
    ka_scores<<<dim3(Bv * Fv * 4), dim3(256), 0, stream>>>(Qws, Mfull, Smx, Ssum);
    kb_out<<<dim3(Bv * Fv * 4), dim3(256), 0, stream>>>(
        inp, Qws, Smx, Ssum, W2T, B2f, a2, (float*)d_out);
}

// Round 15
// 99.788 us; speedup vs baseline: 1.2904x; 1.2904x over previous
//
#include <hip/hip_runtime.h>
#include <math.h>

#define Bv  4
#define Cv  64
#define DCv 32
#define Fv  128
#define Tv  512
#define FT  (Fv * 512)

// ---------------------------------------------------------------------------
// KPREP: fold BN into weights. W1T[k][c] (transposed, for kc1), B1f;
// W2f[o][k] (row-major, for kf), B2f.
// ---------------------------------------------------------------------------
__global__ __launch_bounds__(512)
void kprep(const float* __restrict__ w1, const float* __restrict__ b1,
           const float* __restrict__ g1, const float* __restrict__ be1,
           const float* __restrict__ m1, const float* __restrict__ v1,
           const float* __restrict__ wp, const float* __restrict__ bp,
           const float* __restrict__ g2, const float* __restrict__ be2,
           const float* __restrict__ m2, const float* __restrict__ v2,
           float* __restrict__ W1T, float* __restrict__ B1f,
           float* __restrict__ W2f, float* __restrict__ B2f)
{
    const int tid = threadIdx.x;
    #pragma unroll
    for (int i = 0; i < 4; ++i) {
        const int e = tid * 4 + i;          // W1T: e = k*32 + c
        const int c = e & 31, k = e >> 5;
        W1T[e] = w1[c * Cv + k] * (g1[c] * rsqrtf(v1[c] + 1e-5f));
    }
    {
        const int o = tid >> 3;             // 8 float4 per 32-wide row
        const float s = g2[o] * rsqrtf(v2[o] + 1e-5f);
        float4 v = *(const float4*)&wp[tid * 4];
        v.x *= s; v.y *= s; v.z *= s; v.w *= s;
        *(float4*)&W2f[tid * 4] = v;
    }
    if (tid < DCv) {
        const float s = g1[tid] * rsqrtf(v1[tid] + 1e-5f);
        B1f[tid] = (b1[tid] - m1[tid]) * s + be1[tid];
    }
    if (tid < Cv) {
        const float s = g2[tid] * rsqrtf(v2[tid] + 1e-5f);
        B2f[tid] = (bp[tid] - m2[tid]) * s + be2[tid];
    }
}

// ---------------------------------------------------------------------------
// KC1: streaming conv1, SPILL-PROOF cut. grid (bf, t-quarter) = 2048 x 256.
// Wave = 8 rows, lane = 2 t (float2 coalesced X loads). acc[16]+x2+addr ~ 28
// live regs -> below even a 32-VGPR allocation (r14 lesson). Per k: 1 global
// float2 + 2 broadcast LDS b128 + 16 FMA. X read x4 per block (waves) -> L2.
// ---------------------------------------------------------------------------
#define KROW2(ar, r) \
    acc[(r)*2+0] = fmaf(ar, x.x, acc[(r)*2+0]); \
    acc[(r)*2+1] = fmaf(ar, x.y, acc[(r)*2+1]);

__global__ __launch_bounds__(256, 4)
void kc1_conv(const float* __restrict__ inp,
              const float* __restrict__ W1T, const float* __restrict__ B1f,
              const float* __restrict__ a1,
              float* __restrict__ Qws)
{
    __shared__ __align__(16) float sW[Cv * DCv];   // 8 KB [k][c]
    __shared__ float sB[DCv];

    const int tid = threadIdx.x;
    const int bid = blockIdx.x;
    const int q   = bid & 3;
    const int bf  = bid >> 2;
    const int b   = bf >> 7;
    const int f   = bf & 127;

    {
        const int e = tid * 8;
        *(float4*)&sW[e]     = *(const float4*)&W1T[e];
        *(float4*)&sW[e + 4] = *(const float4*)&W1T[e + 4];
    }
    if (tid < DCv) sB[tid] = B1f[tid];
    const float alpha1 = a1[0];
    __syncthreads();

    const int w  = tid >> 6, l = tid & 63;
    const int r0 = w * 8, tt = l * 2;
    const float* px = inp + (size_t)(b * Cv) * FT + f * 512 + q * 128 + tt;

    float acc[16];
    #pragma unroll
    for (int i = 0; i < 16; ++i) acc[i] = 0.f;

    #pragma unroll 8
    for (int k = 0; k < Cv; ++k) {
        const float2 x   = *(const float2*)&px[(size_t)k * FT];
        const float4 a0  = *(const float4*)&sW[k * DCv + r0];
        const float4 a1v = *(const float4*)&sW[k * DCv + r0 + 4];
        KROW2(a0.x, 0) KROW2(a0.y, 1) KROW2(a0.z, 2) KROW2(a0.w, 3)
        KROW2(a1v.x, 4) KROW2(a1v.y, 5) KROW2(a1v.z, 6) KROW2(a1v.w, 7)
    }

    const float b0 = sB[r0+0], b1_ = sB[r0+1], b2 = sB[r0+2], b3 = sB[r0+3];
    const float b4 = sB[r0+4], b5  = sB[r0+5], b6 = sB[r0+6], b7 = sB[r0+7];
    #pragma unroll
    for (int j = 0; j < 2; ++j) {
        const int t = q * 128 + tt + j;
        float z0 = acc[0*2+j] + b0, z1 = acc[1*2+j] + b1_;
        float z2 = acc[2*2+j] + b2, z3 = acc[3*2+j] + b3;
        float z4 = acc[4*2+j] + b4, z5 = acc[5*2+j] + b5;
        float z6 = acc[6*2+j] + b6, z7 = acc[7*2+j] + b7;
        z0 = z0 >= 0.f ? z0 : alpha1 * z0;  z1 = z1 >= 0.f ? z1 : alpha1 * z1;
        z2 = z2 >= 0.f ? z2 : alpha1 * z2;  z3 = z3 >= 0.f ? z3 : alpha1 * z3;
        z4 = z4 >= 0.f ? z4 : alpha1 * z4;  z5 = z5 >= 0.f ? z5 : alpha1 * z5;
        z6 = z6 >= 0.f ? z6 : alpha1 * z6;  z7 = z7 >= 0.f ? z7 : alpha1 * z7;
        float4 v0; v0.x = z0; v0.y = z1; v0.z = z2; v0.w = z3;
        float4 v1; v1.x = z4; v1.y = z5; v1.z = z6; v1.w = z7;
        float* qg = Qws + ((size_t)bf * Tv + t) * DCv + r0;
        *(float4*)&qg[0] = v0;
        *(float4*)&qg[4] = v1;
    }
}

// ---------------------------------------------------------------------------
// KM: M = Q Q^T / sqrt(32). One block per bf. Proven (~9 us).
// ---------------------------------------------------------------------------
__global__ __launch_bounds__(256)
void km_build(const float* __restrict__ Qws, float* __restrict__ Mfull)
{
    __shared__ __align__(16) float sP[4][1024];  // 16 KB

    const int tid   = threadIdx.x;
    const int bf    = blockIdx.x;
    const int slice = tid >> 6;
    const int l     = tid & 63;
    const int c1b   = l >> 3;
    const int c2b   = l & 7;

    const float* qp = Qws + ((size_t)bf * Tv + slice * 128) * DCv;
    float4 r0 = {0,0,0,0}, r1 = {0,0,0,0}, r2 = {0,0,0,0}, r3 = {0,0,0,0};
    #pragma unroll 4
    for (int i = 0; i < 128; ++i) {
        const float4 qa = *(const float4*)&qp[i * 32 + c1b * 4];
        const float4 qb = *(const float4*)&qp[i * 32 + c2b * 4];
        r0.x = fmaf(qa.x, qb.x, r0.x); r0.y = fmaf(qa.x, qb.y, r0.y);
        r0.z = fmaf(qa.x, qb.z, r0.z); r0.w = fmaf(qa.x, qb.w, r0.w);
        r1.x = fmaf(qa.y, qb.x, r1.x); r1.y = fmaf(qa.y, qb.y, r1.y);
        r1.z = fmaf(qa.y, qb.z, r1.z); r1.w = fmaf(qa.y, qb.w, r1.w);
        r2.x = fmaf(qa.z, qb.x, r2.x); r2.y = fmaf(qa.z, qb.y, r2.y);
        r2.z = fmaf(qa.z, qb.z, r2.z); r2.w = fmaf(qa.z, qb.w, r2.w);
        r3.x = fmaf(qa.w, qb.x, r3.x); r3.y = fmaf(qa.w, qb.y, r3.y);
        r3.z = fmaf(qa.w, qb.z, r3.z); r3.w = fmaf(qa.w, qb.w, r3.w);
    }
    *(float4*)&sP[slice][(c1b * 4 + 0) * DCv + c2b * 4] = r0;
    *(float4*)&sP[slice][(c1b * 4 + 1) * DCv + c2b * 4] = r1;
    *(float4*)&sP[slice][(c1b * 4 + 2) * DCv + c2b * 4] = r2;
    *(float4*)&sP[slice][(c1b * 4 + 3) * DCv + c2b * 4] = r3;
    __syncthreads();

    const float INV = 0.17677669529663687f;  // 1/sqrt(32)
    float4 v0 = *(const float4*)&sP[0][tid * 4];
    float4 v1 = *(const float4*)&sP[1][tid * 4];
    float4 v2 = *(const float4*)&sP[2][tid * 4];
    float4 v3 = *(const float4*)&sP[3][tid * 4];
    float4 o;
    o.x = ((v0.x + v1.x) + (v2.x + v3.x)) * INV;
    o.y = ((v0.y + v1.y) + (v2.y + v3.y)) * INV;
    o.z = ((v0.z + v1.z) + (v2.z + v3.z)) * INV;
    o.w = ((v0.w + v1.w) + (v2.w + v3.w)) * INV;
    *(float4*)&Mfull[(size_t)bf * 1024 + tid * 4] = o;
}

// ---------------------------------------------------------------------------
// KF: fused O=M*Q -> mask -> softmax -> P -> OUT=W2f*P+B2f -> PReLU ->
// +residual. r11 version (measured 52 us, VGPR 84, 0 conflicts) with GEMM1's
// two 4-row tiles sharing x-reads (-32 LDS reads/thread).
// ---------------------------------------------------------------------------
#define GEMM_CC(ACC, cc, a)                                       \
    ACC[(cc)*4+0] = fmaf(a.x, x0.x, ACC[(cc)*4+0]);               \
    ACC[(cc)*4+0] = fmaf(a.y, x1.x, ACC[(cc)*4+0]);               \
    ACC[(cc)*4+0] = fmaf(a.z, x2.x, ACC[(cc)*4+0]);               \
    ACC[(cc)*4+0] = fmaf(a.w, x3.x, ACC[(cc)*4+0]);               \
    ACC[(cc)*4+1] = fmaf(a.x, x0.y, ACC[(cc)*4+1]);               \
    ACC[(cc)*4+1] = fmaf(a.y, x1.y, ACC[(cc)*4+1]);               \
    ACC[(cc)*4+1] = fmaf(a.z, x2.y, ACC[(cc)*4+1]);               \
    ACC[(cc)*4+1] = fmaf(a.w, x3.y, ACC[(cc)*4+1]);               \
    ACC[(cc)*4+2] = fmaf(a.x, x0.z, ACC[(cc)*4+2]);               \
    ACC[(cc)*4+2] = fmaf(a.y, x1.z, ACC[(cc)*4+2]);               \
    ACC[(cc)*4+2] = fmaf(a.z, x2.z, ACC[(cc)*4+2]);               \
    ACC[(cc)*4+2] = fmaf(a.w, x3.z, ACC[(cc)*4+2]);               \
    ACC[(cc)*4+3] = fmaf(a.x, x0.w, ACC[(cc)*4+3]);               \
    ACC[(cc)*4+3] = fmaf(a.y, x1.w, ACC[(cc)*4+3]);               \
    ACC[(cc)*4+3] = fmaf(a.z, x2.w, ACC[(cc)*4+3]);               \
    ACC[(cc)*4+3] = fmaf(a.w, x3.w, ACC[(cc)*4+3]);

#define GEMM_TILE(ACC, SA, row0)                                              \
    _Pragma("unroll")                                                         \
    for (int k0 = 0; k0 < 32; k0 += 4) {                                      \
        const float4 x0 = *(const float4*)&sX[(k0+0)*Tv + t0];                \
        const float4 x1 = *(const float4*)&sX[(k0+1)*Tv + t0];                \
        const float4 x2 = *(const float4*)&sX[(k0+2)*Tv + t0];                \
        const float4 x3 = *(const float4*)&sX[(k0+3)*Tv + t0];                \
        { const float4 a = *(const float4*)&(SA)[((row0)+0)*36 + k0]; GEMM_CC(ACC,0,a) } \
        { const float4 a = *(const float4*)&(SA)[((row0)+1)*36 + k0]; GEMM_CC(ACC,1,a) } \
        { const float4 a = *(const float4*)&(SA)[((row0)+2)*36 + k0]; GEMM_CC(ACC,2,a) } \
        { const float4 a = *(const float4*)&(SA)[((row0)+3)*36 + k0]; GEMM_CC(ACC,3,a) } \
    }

__global__ __launch_bounds__(512, 2)
void kf_fused(const float* __restrict__ inp,
              const float* __restrict__ Qws, const float* __restrict__ Mfull,
              const float* __restrict__ W2f, const float* __restrict__ B2f,
              const float* __restrict__ a2,
              float* __restrict__ out)
{
    __shared__ __align__(16) float sX[DCv * Tv];   // 64 KB [k][t]: Q, then P
    __shared__ __align__(16) float sM[DCv * 36];   // 4.5 KB
    __shared__ __align__(16) float sW[Cv * 36];    // 9 KB
    __shared__ float sPart[8][DCv];
    __shared__ float sMx[DCv], sRZ[DCv];
    __shared__ float sB2[Cv];

    const int tid = threadIdx.x;
    const int bf  = blockIdx.x;
    const int b   = bf >> 7;
    const int f   = bf & 127;
    const int w   = tid >> 6;
    const int l   = tid & 63;
    const int tl  = l & 15;
    const int cl  = l >> 4;
    const int t0  = w * 64 + tl * 4;          // this lane's 4 t-columns
    const int limit = f + (Tv - Fv + 1);      // valid iff t < limit (385..512)
    const float alpha2 = a2[0];

    // ---- stage: q column, M, W2f, B2f ----
    const float* qg = Qws + ((size_t)bf * Tv + tid) * DCv;
    float4 q0 = *(const float4*)&qg[0],  q1 = *(const float4*)&qg[4];
    float4 q2 = *(const float4*)&qg[8],  q3 = *(const float4*)&qg[12];
    float4 q4 = *(const float4*)&qg[16], q5 = *(const float4*)&qg[20];
    float4 q6 = *(const float4*)&qg[24], q7 = *(const float4*)&qg[28];

    if (tid < 256) {
        const int c = tid >> 3, k0 = (tid & 7) << 2;
        float4 v = *(const float4*)&Mfull[(size_t)bf * 1024 + tid * 4];
        *(float4*)&sM[c * 36 + k0] = v;
    }
    {
        const int c = tid >> 3, k0 = (tid & 7) << 2;
        float4 v = *(const float4*)&W2f[tid * 4];
        *(float4*)&sW[c * 36 + k0] = v;
    }
    if (tid < Cv) sB2[tid] = B2f[tid];

    {
        const int t = tid;
        sX[ 0*Tv+t]=q0.x; sX[ 1*Tv+t]=q0.y; sX[ 2*Tv+t]=q0.z; sX[ 3*Tv+t]=q0.w;
        sX[ 4*Tv+t]=q1.x; sX[ 5*Tv+t]=q1.y; sX[ 6*Tv+t]=q1.z; sX[ 7*Tv+t]=q1.w;
        sX[ 8*Tv+t]=q2.x; sX[ 9*Tv+t]=q2.y; sX[10*Tv+t]=q2.z; sX[11*Tv+t]=q2.w;
        sX[12*Tv+t]=q3.x; sX[13*Tv+t]=q3.y; sX[14*Tv+t]=q3.z; sX[15*Tv+t]=q3.w;
        sX[16*Tv+t]=q4.x; sX[17*Tv+t]=q4.y; sX[18*Tv+t]=q4.z; sX[19*Tv+t]=q4.w;
        sX[20*Tv+t]=q5.x; sX[21*Tv+t]=q5.y; sX[22*Tv+t]=q5.z; sX[23*Tv+t]=q5.w;
        sX[24*Tv+t]=q6.x; sX[25*Tv+t]=q6.y; sX[26*Tv+t]=q6.z; sX[27*Tv+t]=q6.w;
        sX[28*Tv+t]=q7.x; sX[29*Tv+t]=q7.y; sX[30*Tv+t]=q7.z; sX[31*Tv+t]=q7.w;
    }
    __syncthreads();

    // ---- GEMM1: O[32c][t], two 4-row tiles SHARING x-reads ----
    float oA[16], oB[16];
    #pragma unroll
    for (int i = 0; i < 16; ++i) { oA[i] = 0.f; oB[i] = 0.f; }
    const int cA = cl * 4;
    const int cB = 16 + cl * 4;
    #pragma unroll
    for (int k0 = 0; k0 < 32; k0 += 4) {
        const float4 x0 = *(const float4*)&sX[(k0+0)*Tv + t0];
        const float4 x1 = *(const float4*)&sX[(k0+1)*Tv + t0];
        const float4 x2 = *(const float4*)&sX[(k0+2)*Tv + t0];
        const float4 x3 = *(const float4*)&sX[(k0+3)*Tv + t0];
        { const float4 a = *(const float4*)&sM[(cA+0)*36 + k0]; GEMM_CC(oA,0,a) }
        { const float4 a = *(const float4*)&sM[(cA+1)*36 + k0]; GEMM_CC(oA,1,a) }
        { const float4 a = *(const float4*)&sM[(cA+2)*36 + k0]; GEMM_CC(oA,2,a) }
        { const float4 a = *(const float4*)&sM[(cA+3)*36 + k0]; GEMM_CC(oA,3,a) }
        { const float4 a = *(const float4*)&sM[(cB+0)*36 + k0]; GEMM_CC(oB,0,a) }
        { const float4 a = *(const float4*)&sM[(cB+1)*36 + k0]; GEMM_CC(oB,1,a) }
        { const float4 a = *(const float4*)&sM[(cB+2)*36 + k0]; GEMM_CC(oB,2,a) }
        { const float4 a = *(const float4*)&sM[(cB+3)*36 + k0]; GEMM_CC(oB,3,a) }
    }

    // ---- mask ----
    #pragma unroll
    for (int jt = 0; jt < 4; ++jt) {
        if (t0 + jt >= limit) {
            #pragma unroll
            for (int cc = 0; cc < 4; ++cc) { oA[cc*4+jt] = -INFINITY; oB[cc*4+jt] = -INFINITY; }
        }
    }

    // ---- stats pass 1: per-(wave,c) max ----
    #pragma unroll
    for (int cc = 0; cc < 4; ++cc) {
        float mA = fmaxf(fmaxf(oA[cc*4+0], oA[cc*4+1]), fmaxf(oA[cc*4+2], oA[cc*4+3]));
        float mB = fmaxf(fmaxf(oB[cc*4+0], oB[cc*4+1]), fmaxf(oB[cc*4+2], oB[cc*4+3]));
        #pragma unroll
        for (int s = 1; s < 16; s <<= 1) {
            mA = fmaxf(mA, __shfl_xor(mA, s));
            mB = fmaxf(mB, __shfl_xor(mB, s));
        }
        if (tl == 0) { sPart[w][cA + cc] = mA; sPart[w][cB + cc] = mB; }
    }
    __syncthreads();
    if (tid < DCv) {
        float m = sPart[0][tid];
        #pragma unroll
        for (int ww = 1; ww < 8; ++ww) m = fmaxf(m, sPart[ww][tid]);
        sMx[tid] = m;
    }
    __syncthreads();

    // ---- exp + pass 2: per-(wave,c) sum ----
    #pragma unroll
    for (int cc = 0; cc < 4; ++cc) {
        const float mxA = sMx[cA + cc], mxB = sMx[cB + cc];
        float sA = 0.f, sB = 0.f;
        #pragma unroll
        for (int jt = 0; jt < 4; ++jt) {
            oA[cc*4+jt] = __expf(oA[cc*4+jt] - mxA); sA += oA[cc*4+jt];
            oB[cc*4+jt] = __expf(oB[cc*4+jt] - mxB); sB += oB[cc*4+jt];
        }
        #pragma unroll
        for (int s = 1; s < 16; s <<= 1) {
            sA += __shfl_xor(sA, s);
            sB += __shfl_xor(sB, s);
        }
        if (tl == 0) { sPart[w][cA + cc] = sA; sPart[w][cB + cc] = sB; }
    }
    __syncthreads();
    if (tid < DCv) {
        float z = 0.f;
        #pragma unroll
        for (int ww = 0; ww < 8; ++ww) z += sPart[ww][tid];
        sRZ[tid] = 1.f / z;
    }
    __syncthreads();

    // ---- P = e * rz -> overwrite sX ----
    #pragma unroll
    for (int cc = 0; cc < 4; ++cc) {
        const float rA = sRZ[cA + cc], rB = sRZ[cB + cc];
        float4 pA, pB;
        pA.x = oA[cc*4+0]*rA; pA.y = oA[cc*4+1]*rA; pA.z = oA[cc*4+2]*rA; pA.w = oA[cc*4+3]*rA;
        pB.x = oB[cc*4+0]*rB; pB.y = oB[cc*4+1]*rB; pB.z = oB[cc*4+2]*rB; pB.w = oB[cc*4+3]*rB;
        *(float4*)&sX[(cA + cc)*Tv + t0] = pA;
        *(float4*)&sX[(cB + cc)*Tv + t0] = pB;
    }
    __syncthreads();

    // ---- GEMM2: OUT[64oc][t] in four 16oc iterations + fused epilogue ----
    #pragma unroll 1
    for (int it = 0; it < 4; ++it) {
        const int oc0 = it * 16 + cl * 4;
        const float* rp = inp + ((size_t)(b * Cv + oc0) * Fv + f) * Tv + t0;
        float4 r0 = *(const float4*)&rp[0];
        float4 r1 = *(const float4*)&rp[(size_t)1 * FT];
        float4 r2 = *(const float4*)&rp[(size_t)2 * FT];
        float4 r3 = *(const float4*)&rp[(size_t)3 * FT];

        float acc[16];
        #pragma unroll
        for (int i = 0; i < 16; ++i) acc[i] = 0.f;
        GEMM_TILE(acc, sW, oc0)

        float* po = out + ((size_t)(b * Cv + oc0) * Fv + f) * Tv + t0;
        #define EPI(cc, RV, ROWOFF) {                                         \
            const float bb = sB2[oc0 + (cc)];                                 \
            float z0 = acc[(cc)*4+0] + bb, z1 = acc[(cc)*4+1] + bb;           \
            float z2 = acc[(cc)*4+2] + bb, z3 = acc[(cc)*4+3] + bb;           \
            z0 = z0 >= 0.f ? z0 : alpha2 * z0;                                \
            z1 = z1 >= 0.f ? z1 : alpha2 * z1;                                \
            z2 = z2 >= 0.f ? z2 : alpha2 * z2;                                \
            z3 = z3 >= 0.f ? z3 : alpha2 * z3;                                \
            float4 o4; o4.x = z0 + RV.x; o4.y = z1 + RV.y;                    \
            o4.z = z2 + RV.z; o4.w = z3 + RV.w;                               \
            *(float4*)&po[(size_t)(ROWOFF) * FT] = o4; }
        EPI(0, r0, 0)
        EPI(1, r1, 1)
        EPI(2, r2, 2)
        EPI(3, r3, 3)
        #undef EPI
    }
}

extern "C" void kernel_launch(void* const* d_in, const int* in_sizes, int n_in,
                              void* d_out, int out_size, void* d_ws, size_t ws_size,
                              hipStream_t stream) {
    const float* inp = (const float*)d_in[0];
    const float* w1  = (const float*)d_in[1];
    const float* b1  = (const float*)d_in[2];
    const float* g1  = (const float*)d_in[3];
    const float* be1 = (const float*)d_in[4];
    const float* m1  = (const float*)d_in[5];
    const float* v1  = (const float*)d_in[6];
    const float* a1  = (const float*)d_in[7];
    const float* wp  = (const float*)d_in[8];
    const float* bp  = (const float*)d_in[9];
    const float* g2  = (const float*)d_in[10];
    const float* be2 = (const float*)d_in[11];
    const float* m2  = (const float*)d_in[12];
    const float* v2  = (const float*)d_in[13];
    const float* a2  = (const float*)d_in[14];

    float* Qws   = (float*)d_ws;                            // 8,388,608 f = 33.6 MB
    float* Mfull = Qws   + (size_t)Bv * Fv * Tv * DCv;      //   524,288 f =  2.1 MB
    float* W1T   = Mfull + (size_t)512 * 1024;              //     2,048 f
    float* B1f   = W1T   + 2048;                            //        32 f
    float* W2f   = B1f   + 32;                              //     2,048 f
    float* B2f   = W2f   + 2048;                            //        64 f

    kprep<<<dim3(1), dim3(512), 0, stream>>>(
        w1, b1, g1, be1, m1, v1, wp, bp, g2, be2, m2, v2, W1T, B1f, W2f, B2f);
    kc1_conv<<<dim3(Bv * Fv * 4), dim3(256), 0, stream>>>(inp, W1T, B1f, a1, Qws);
    km_build<<<dim3(Bv * Fv), dim3(256), 0, stream>>>(Qws, Mfull);
    kf_fused<<<dim3(Bv * Fv), dim3(512), 0, stream>>>(
        inp, Qws, Mfull, W2f, B2f, a2, (float*)d_out);
}

// Round 16
// 93.947 us; speedup vs baseline: 1.3706x; 1.0622x over previous
//
#include <hip/hip_runtime.h>
#include <math.h>

#define Bv  4
#define Cv  64
#define DCv 32
#define Fv  128
#define Tv  512
#define FT  (Fv * 512)

// ---------------------------------------------------------------------------
// KPREP: fold BN into weights. W1T[k][c] (transposed, for kc1), B1f;
// W2f[o][k] (row-major, for kf), B2f.
// ---------------------------------------------------------------------------
__global__ __launch_bounds__(512)
void kprep(const float* __restrict__ w1, const float* __restrict__ b1,
           const float* __restrict__ g1, const float* __restrict__ be1,
           const float* __restrict__ m1, const float* __restrict__ v1,
           const float* __restrict__ wp, const float* __restrict__ bp,
           const float* __restrict__ g2, const float* __restrict__ be2,
           const float* __restrict__ m2, const float* __restrict__ v2,
           float* __restrict__ W1T, float* __restrict__ B1f,
           float* __restrict__ W2f, float* __restrict__ B2f)
{
    const int tid = threadIdx.x;
    #pragma unroll
    for (int i = 0; i < 4; ++i) {
        const int e = tid * 4 + i;          // W1T: e = k*32 + c
        const int c = e & 31, k = e >> 5;
        W1T[e] = w1[c * Cv + k] * (g1[c] * rsqrtf(v1[c] + 1e-5f));
    }
    {
        const int o = tid >> 3;             // 8 float4 per 32-wide row
        const float s = g2[o] * rsqrtf(v2[o] + 1e-5f);
        float4 v = *(const float4*)&wp[tid * 4];
        v.x *= s; v.y *= s; v.z *= s; v.w *= s;
        *(float4*)&W2f[tid * 4] = v;
    }
    if (tid < DCv) {
        const float s = g1[tid] * rsqrtf(v1[tid] + 1e-5f);
        B1f[tid] = (b1[tid] - m1[tid]) * s + be1[tid];
    }
    if (tid < Cv) {
        const float s = g2[tid] * rsqrtf(v2[tid] + 1e-5f);
        B2f[tid] = (bp[tid] - m2[tid]) * s + be2[tid];
    }
}

// ---------------------------------------------------------------------------
// KC1: conv1, km-shaped. grid (bf, t-quarter) = 2048 x 256 (4 waves).
// Wave w: rh = w&1 (row-half, 16 rows), tc = w>>1 (64-t chunk). Lane:
// tl = l&15 (4 t), cl = l>>4 (4-row group). Per k: 1 global b128 (X, f4,
// 4-way addr-shared across cl -> coalesced) + 1 LDS b128 (W1T broadcast)
// + 16 FMA. acc[16] -> ~36 VGPR no-spill (r15-proven shape). 8 blocks/CU.
// ---------------------------------------------------------------------------
__global__ __launch_bounds__(256, 4)
void kc1_conv(const float* __restrict__ inp,
              const float* __restrict__ W1T, const float* __restrict__ B1f,
              const float* __restrict__ a1,
              float* __restrict__ Qws)
{
    __shared__ __align__(16) float sW[Cv * DCv];   // 8 KB [k][c]
    __shared__ float sB[DCv];

    const int tid = threadIdx.x;
    const int bid = blockIdx.x;
    const int q   = bid & 3;
    const int bf  = bid >> 2;
    const int b   = bf >> 7;
    const int f   = bf & 127;

    {
        const int e = tid * 8;
        *(float4*)&sW[e]     = *(const float4*)&W1T[e];
        *(float4*)&sW[e + 4] = *(const float4*)&W1T[e + 4];
    }
    if (tid < DCv) sB[tid] = B1f[tid];
    const float alpha1 = a1[0];
    __syncthreads();

    const int w  = tid >> 6, l = tid & 63;
    const int rh = w & 1, tc = w >> 1;
    const int tl = l & 15, cl = l >> 4;
    const int r0 = rh * 16 + cl * 4;
    const int t0 = q * 128 + tc * 64 + tl * 4;

    const float* px = inp + (size_t)(b * Cv) * FT + f * 512 + t0;

    float acc[16];
    #pragma unroll
    for (int i = 0; i < 16; ++i) acc[i] = 0.f;

    #pragma unroll 8
    for (int k = 0; k < Cv; ++k) {
        const float4 x = *(const float4*)&px[(size_t)k * FT];
        const float4 a = *(const float4*)&sW[k * DCv + r0];
        acc[0*4+0] = fmaf(a.x, x.x, acc[0*4+0]); acc[0*4+1] = fmaf(a.x, x.y, acc[0*4+1]);
        acc[0*4+2] = fmaf(a.x, x.z, acc[0*4+2]); acc[0*4+3] = fmaf(a.x, x.w, acc[0*4+3]);
        acc[1*4+0] = fmaf(a.y, x.x, acc[1*4+0]); acc[1*4+1] = fmaf(a.y, x.y, acc[1*4+1]);
        acc[1*4+2] = fmaf(a.y, x.z, acc[1*4+2]); acc[1*4+3] = fmaf(a.y, x.w, acc[1*4+3]);
        acc[2*4+0] = fmaf(a.z, x.x, acc[2*4+0]); acc[2*4+1] = fmaf(a.z, x.y, acc[2*4+1]);
        acc[2*4+2] = fmaf(a.z, x.z, acc[2*4+2]); acc[2*4+3] = fmaf(a.z, x.w, acc[2*4+3]);
        acc[3*4+0] = fmaf(a.w, x.x, acc[3*4+0]); acc[3*4+1] = fmaf(a.w, x.y, acc[3*4+1]);
        acc[3*4+2] = fmaf(a.w, x.z, acc[3*4+2]); acc[3*4+3] = fmaf(a.w, x.w, acc[3*4+3]);
    }

    const float b0 = sB[r0+0], b1_ = sB[r0+1], b2 = sB[r0+2], b3 = sB[r0+3];
    #pragma unroll
    for (int j = 0; j < 4; ++j) {
        float z0 = acc[0*4+j] + b0, z1 = acc[1*4+j] + b1_;
        float z2 = acc[2*4+j] + b2, z3 = acc[3*4+j] + b3;
        z0 = z0 >= 0.f ? z0 : alpha1 * z0;  z1 = z1 >= 0.f ? z1 : alpha1 * z1;
        z2 = z2 >= 0.f ? z2 : alpha1 * z2;  z3 = z3 >= 0.f ? z3 : alpha1 * z3;
        float4 v; v.x = z0; v.y = z1; v.z = z2; v.w = z3;
        *(float4*)&Qws[((size_t)bf * Tv + t0 + j) * DCv + r0] = v;
    }
}

// ---------------------------------------------------------------------------
// KM: M = Q Q^T / sqrt(32). One block per bf. Proven (~9 us, 60 TF).
// ---------------------------------------------------------------------------
__global__ __launch_bounds__(256)
void km_build(const float* __restrict__ Qws, float* __restrict__ Mfull)
{
    __shared__ __align__(16) float sP[4][1024];  // 16 KB

    const int tid   = threadIdx.x;
    const int bf    = blockIdx.x;
    const int slice = tid >> 6;
    const int l     = tid & 63;
    const int c1b   = l >> 3;
    const int c2b   = l & 7;

    const float* qp = Qws + ((size_t)bf * Tv + slice * 128) * DCv;
    float4 r0 = {0,0,0,0}, r1 = {0,0,0,0}, r2 = {0,0,0,0}, r3 = {0,0,0,0};
    #pragma unroll 4
    for (int i = 0; i < 128; ++i) {
        const float4 qa = *(const float4*)&qp[i * 32 + c1b * 4];
        const float4 qb = *(const float4*)&qp[i * 32 + c2b * 4];
        r0.x = fmaf(qa.x, qb.x, r0.x); r0.y = fmaf(qa.x, qb.y, r0.y);
        r0.z = fmaf(qa.x, qb.z, r0.z); r0.w = fmaf(qa.x, qb.w, r0.w);
        r1.x = fmaf(qa.y, qb.x, r1.x); r1.y = fmaf(qa.y, qb.y, r1.y);
        r1.z = fmaf(qa.y, qb.z, r1.z); r1.w = fmaf(qa.y, qb.w, r1.w);
        r2.x = fmaf(qa.z, qb.x, r2.x); r2.y = fmaf(qa.z, qb.y, r2.y);
        r2.z = fmaf(qa.z, qb.z, r2.z); r2.w = fmaf(qa.z, qb.w, r2.w);
        r3.x = fmaf(qa.w, qb.x, r3.x); r3.y = fmaf(qa.w, qb.y, r3.y);
        r3.z = fmaf(qa.w, qb.z, r3.z); r3.w = fmaf(qa.w, qb.w, r3.w);
    }
    *(float4*)&sP[slice][(c1b * 4 + 0) * DCv + c2b * 4] = r0;
    *(float4*)&sP[slice][(c1b * 4 + 1) * DCv + c2b * 4] = r1;
    *(float4*)&sP[slice][(c1b * 4 + 2) * DCv + c2b * 4] = r2;
    *(float4*)&sP[slice][(c1b * 4 + 3) * DCv + c2b * 4] = r3;
    __syncthreads();

    const float INV = 0.17677669529663687f;  // 1/sqrt(32)
    float4 v0 = *(const float4*)&sP[0][tid * 4];
    float4 v1 = *(const float4*)&sP[1][tid * 4];
    float4 v2 = *(const float4*)&sP[2][tid * 4];
    float4 v3 = *(const float4*)&sP[3][tid * 4];
    float4 o;
    o.x = ((v0.x + v1.x) + (v2.x + v3.x)) * INV;
    o.y = ((v0.y + v1.y) + (v2.y + v3.y)) * INV;
    o.z = ((v0.z + v1.z) + (v2.z + v3.z)) * INV;
    o.w = ((v0.w + v1.w) + (v2.w + v3.w)) * INV;
    *(float4*)&Mfull[(size_t)bf * 1024 + tid * 4] = o;
}

// ---------------------------------------------------------------------------
// KF: fused O=M*Q -> mask -> softmax -> P -> OUT=W2f*P+B2f -> PReLU ->
// +residual. r15 base (51 us) with GEMM2 as 2 iterations of 8-row tiles
// sharing x-reads (256 -> 192 LDS b128/thread); residual loads after GEMM.
// ---------------------------------------------------------------------------
#define GEMM_CC(ACC, cc, a)                                       \
    ACC[(cc)*4+0] = fmaf(a.x, x0.x, ACC[(cc)*4+0]);               \
    ACC[(cc)*4+0] = fmaf(a.y, x1.x, ACC[(cc)*4+0]);               \
    ACC[(cc)*4+0] = fmaf(a.z, x2.x, ACC[(cc)*4+0]);               \
    ACC[(cc)*4+0] = fmaf(a.w, x3.x, ACC[(cc)*4+0]);               \
    ACC[(cc)*4+1] = fmaf(a.x, x0.y, ACC[(cc)*4+1]);               \
    ACC[(cc)*4+1] = fmaf(a.y, x1.y, ACC[(cc)*4+1]);               \
    ACC[(cc)*4+1] = fmaf(a.z, x2.y, ACC[(cc)*4+1]);               \
    ACC[(cc)*4+1] = fmaf(a.w, x3.y, ACC[(cc)*4+1]);               \
    ACC[(cc)*4+2] = fmaf(a.x, x0.z, ACC[(cc)*4+2]);               \
    ACC[(cc)*4+2] = fmaf(a.y, x1.z, ACC[(cc)*4+2]);               \
    ACC[(cc)*4+2] = fmaf(a.z, x2.z, ACC[(cc)*4+2]);               \
    ACC[(cc)*4+2] = fmaf(a.w, x3.z, ACC[(cc)*4+2]);               \
    ACC[(cc)*4+3] = fmaf(a.x, x0.w, ACC[(cc)*4+3]);               \
    ACC[(cc)*4+3] = fmaf(a.y, x1.w, ACC[(cc)*4+3]);               \
    ACC[(cc)*4+3] = fmaf(a.z, x2.w, ACC[(cc)*4+3]);               \
    ACC[(cc)*4+3] = fmaf(a.w, x3.w, ACC[(cc)*4+3]);

__global__ __launch_bounds__(512, 2)
void kf_fused(const float* __restrict__ inp,
              const float* __restrict__ Qws, const float* __restrict__ Mfull,
              const float* __restrict__ W2f, const float* __restrict__ B2f,
              const float* __restrict__ a2,
              float* __restrict__ out)
{
    __shared__ __align__(16) float sX[DCv * Tv];   // 64 KB [k][t]: Q, then P
    __shared__ __align__(16) float sM[DCv * 36];   // 4.5 KB
    __shared__ __align__(16) float sW[Cv * 36];    // 9 KB
    __shared__ float sPart[8][DCv];
    __shared__ float sMx[DCv], sRZ[DCv];
    __shared__ float sB2[Cv];

    const int tid = threadIdx.x;
    const int bf  = blockIdx.x;
    const int b   = bf >> 7;
    const int f   = bf & 127;
    const int w   = tid >> 6;
    const int l   = tid & 63;
    const int tl  = l & 15;
    const int cl  = l >> 4;
    const int t0  = w * 64 + tl * 4;          // this lane's 4 t-columns
    const int limit = f + (Tv - Fv + 1);      // valid iff t < limit (385..512)
    const float alpha2 = a2[0];

    // ---- stage: q column, M, W2f, B2f ----
    const float* qg = Qws + ((size_t)bf * Tv + tid) * DCv;
    float4 q0 = *(const float4*)&qg[0],  q1 = *(const float4*)&qg[4];
    float4 q2 = *(const float4*)&qg[8],  q3 = *(const float4*)&qg[12];
    float4 q4 = *(const float4*)&qg[16], q5 = *(const float4*)&qg[20];
    float4 q6 = *(const float4*)&qg[24], q7 = *(const float4*)&qg[28];

    if (tid < 256) {
        const int c = tid >> 3, k0 = (tid & 7) << 2;
        float4 v = *(const float4*)&Mfull[(size_t)bf * 1024 + tid * 4];
        *(float4*)&sM[c * 36 + k0] = v;
    }
    {
        const int c = tid >> 3, k0 = (tid & 7) << 2;
        float4 v = *(const float4*)&W2f[tid * 4];
        *(float4*)&sW[c * 36 + k0] = v;
    }
    if (tid < Cv) sB2[tid] = B2f[tid];

    {
        const int t = tid;
        sX[ 0*Tv+t]=q0.x; sX[ 1*Tv+t]=q0.y; sX[ 2*Tv+t]=q0.z; sX[ 3*Tv+t]=q0.w;
        sX[ 4*Tv+t]=q1.x; sX[ 5*Tv+t]=q1.y; sX[ 6*Tv+t]=q1.z; sX[ 7*Tv+t]=q1.w;
        sX[ 8*Tv+t]=q2.x; sX[ 9*Tv+t]=q2.y; sX[10*Tv+t]=q2.z; sX[11*Tv+t]=q2.w;
        sX[12*Tv+t]=q3.x; sX[13*Tv+t]=q3.y; sX[14*Tv+t]=q3.z; sX[15*Tv+t]=q3.w;
        sX[16*Tv+t]=q4.x; sX[17*Tv+t]=q4.y; sX[18*Tv+t]=q4.z; sX[19*Tv+t]=q4.w;
        sX[20*Tv+t]=q5.x; sX[21*Tv+t]=q5.y; sX[22*Tv+t]=q5.z; sX[23*Tv+t]=q5.w;
        sX[24*Tv+t]=q6.x; sX[25*Tv+t]=q6.y; sX[26*Tv+t]=q6.z; sX[27*Tv+t]=q6.w;
        sX[28*Tv+t]=q7.x; sX[29*Tv+t]=q7.y; sX[30*Tv+t]=q7.z; sX[31*Tv+t]=q7.w;
    }
    __syncthreads();

    // ---- GEMM1: O[32c][t], two 4-row tiles SHARING x-reads ----
    float oA[16], oB[16];
    #pragma unroll
    for (int i = 0; i < 16; ++i) { oA[i] = 0.f; oB[i] = 0.f; }
    const int cA = cl * 4;
    const int cB = 16 + cl * 4;
    #pragma unroll
    for (int k0 = 0; k0 < 32; k0 += 4) {
        const float4 x0 = *(const float4*)&sX[(k0+0)*Tv + t0];
        const float4 x1 = *(const float4*)&sX[(k0+1)*Tv + t0];
        const float4 x2 = *(const float4*)&sX[(k0+2)*Tv + t0];
        const float4 x3 = *(const float4*)&sX[(k0+3)*Tv + t0];
        { const float4 a = *(const float4*)&sM[(cA+0)*36 + k0]; GEMM_CC(oA,0,a) }
        { const float4 a = *(const float4*)&sM[(cA+1)*36 + k0]; GEMM_CC(oA,1,a) }
        { const float4 a = *(const float4*)&sM[(cA+2)*36 + k0]; GEMM_CC(oA,2,a) }
        { const float4 a = *(const float4*)&sM[(cA+3)*36 + k0]; GEMM_CC(oA,3,a) }
        { const float4 a = *(const float4*)&sM[(cB+0)*36 + k0]; GEMM_CC(oB,0,a) }
        { const float4 a = *(const float4*)&sM[(cB+1)*36 + k0]; GEMM_CC(oB,1,a) }
        { const float4 a = *(const float4*)&sM[(cB+2)*36 + k0]; GEMM_CC(oB,2,a) }
        { const float4 a = *(const float4*)&sM[(cB+3)*36 + k0]; GEMM_CC(oB,3,a) }
    }

    // ---- mask ----
    #pragma unroll
    for (int jt = 0; jt < 4; ++jt) {
        if (t0 + jt >= limit) {
            #pragma unroll
            for (int cc = 0; cc < 4; ++cc) { oA[cc*4+jt] = -INFINITY; oB[cc*4+jt] = -INFINITY; }
        }
    }

    // ---- stats pass 1: per-(wave,c) max ----
    #pragma unroll
    for (int cc = 0; cc < 4; ++cc) {
        float mA = fmaxf(fmaxf(oA[cc*4+0], oA[cc*4+1]), fmaxf(oA[cc*4+2], oA[cc*4+3]));
        float mB = fmaxf(fmaxf(oB[cc*4+0], oB[cc*4+1]), fmaxf(oB[cc*4+2], oB[cc*4+3]));
        #pragma unroll
        for (int s = 1; s < 16; s <<= 1) {
            mA = fmaxf(mA, __shfl_xor(mA, s));
            mB = fmaxf(mB, __shfl_xor(mB, s));
        }
        if (tl == 0) { sPart[w][cA + cc] = mA; sPart[w][cB + cc] = mB; }
    }
    __syncthreads();
    if (tid < DCv) {
        float m = sPart[0][tid];
        #pragma unroll
        for (int ww = 1; ww < 8; ++ww) m = fmaxf(m, sPart[ww][tid]);
        sMx[tid] = m;
    }
    __syncthreads();

    // ---- exp + pass 2: per-(wave,c) sum ----
    #pragma unroll
    for (int cc = 0; cc < 4; ++cc) {
        const float mxA = sMx[cA + cc], mxB = sMx[cB + cc];
        float sA = 0.f, sB = 0.f;
        #pragma unroll
        for (int jt = 0; jt < 4; ++jt) {
            oA[cc*4+jt] = __expf(oA[cc*4+jt] - mxA); sA += oA[cc*4+jt];
            oB[cc*4+jt] = __expf(oB[cc*4+jt] - mxB); sB += oB[cc*4+jt];
        }
        #pragma unroll
        for (int s = 1; s < 16; s <<= 1) {
            sA += __shfl_xor(sA, s);
            sB += __shfl_xor(sB, s);
        }
        if (tl == 0) { sPart[w][cA + cc] = sA; sPart[w][cB + cc] = sB; }
    }
    __syncthreads();
    if (tid < DCv) {
        float z = 0.f;
        #pragma unroll
        for (int ww = 0; ww < 8; ++ww) z += sPart[ww][tid];
        sRZ[tid] = 1.f / z;
    }
    __syncthreads();

    // ---- P = e * rz -> overwrite sX ----
    #pragma unroll
    for (int cc = 0; cc < 4; ++cc) {
        const float rA = sRZ[cA + cc], rB = sRZ[cB + cc];
        float4 pA, pB;
        pA.x = oA[cc*4+0]*rA; pA.y = oA[cc*4+1]*rA; pA.z = oA[cc*4+2]*rA; pA.w = oA[cc*4+3]*rA;
        pB.x = oB[cc*4+0]*rB; pB.y = oB[cc*4+1]*rB; pB.z = oB[cc*4+2]*rB; pB.w = oB[cc*4+3]*rB;
        *(float4*)&sX[(cA + cc)*Tv + t0] = pA;
        *(float4*)&sX[(cB + cc)*Tv + t0] = pB;
    }
    __syncthreads();

    // ---- GEMM2: OUT[64oc][t] in TWO 8-row-tile iterations (x-reads shared) ----
    #pragma unroll 1
    for (int it = 0; it < 2; ++it) {
        const int oc0 = it * 32 + cl * 8;

        float acc[32];
        #pragma unroll
        for (int i = 0; i < 32; ++i) acc[i] = 0.f;

        #pragma unroll
        for (int k0 = 0; k0 < 32; k0 += 4) {
            const float4 x0 = *(const float4*)&sX[(k0+0)*Tv + t0];
            const float4 x1 = *(const float4*)&sX[(k0+1)*Tv + t0];
            const float4 x2 = *(const float4*)&sX[(k0+2)*Tv + t0];
            const float4 x3 = *(const float4*)&sX[(k0+3)*Tv + t0];
            { const float4 a = *(const float4*)&sW[(oc0+0)*36 + k0]; GEMM_CC(acc,0,a) }
            { const float4 a = *(const float4*)&sW[(oc0+1)*36 + k0]; GEMM_CC(acc,1,a) }
            { const float4 a = *(const float4*)&sW[(oc0+2)*36 + k0]; GEMM_CC(acc,2,a) }
            { const float4 a = *(const float4*)&sW[(oc0+3)*36 + k0]; GEMM_CC(acc,3,a) }
            { const float4 a = *(const float4*)&sW[(oc0+4)*36 + k0]; GEMM_CC(acc,4,a) }
            { const float4 a = *(const float4*)&sW[(oc0+5)*36 + k0]; GEMM_CC(acc,5,a) }
            { const float4 a = *(const float4*)&sW[(oc0+6)*36 + k0]; GEMM_CC(acc,6,a) }
            { const float4 a = *(const float4*)&sW[(oc0+7)*36 + k0]; GEMM_CC(acc,7,a) }
        }

        const float* rp = inp + ((size_t)(b * Cv + oc0) * Fv + f) * Tv + t0;
        float*       po = out + ((size_t)(b * Cv + oc0) * Fv + f) * Tv + t0;
        #pragma unroll
        for (int r = 0; r < 8; ++r) {
            const float4 rv = *(const float4*)&rp[(size_t)r * FT];
            const float bb = sB2[oc0 + r];
            float z0 = acc[r*4+0] + bb, z1 = acc[r*4+1] + bb;
            float z2 = acc[r*4+2] + bb, z3 = acc[r*4+3] + bb;
            z0 = z0 >= 0.f ? z0 : alpha2 * z0;
            z1 = z1 >= 0.f ? z1 : alpha2 * z1;
            z2 = z2 >= 0.f ? z2 : alpha2 * z2;
            z3 = z3 >= 0.f ? z3 : alpha2 * z3;
            float4 o4; o4.x = z0 + rv.x; o4.y = z1 + rv.y;
            o4.z = z2 + rv.z; o4.w = z3 + rv.w;
            *(float4*)&po[(size_t)r * FT] = o4;
        }
    }
}

extern "C" void kernel_launch(void* const* d_in, const int* in_sizes, int n_in,
                              void* d_out, int out_size, void* d_ws, size_t ws_size,
                              hipStream_t stream) {
    const float* inp = (const float*)d_in[0];
    const float* w1  = (const float*)d_in[1];
    const float* b1  = (const float*)d_in[2];
    const float* g1  = (const float*)d_in[3];
    const float* be1 = (const float*)d_in[4];
    const float* m1  = (const float*)d_in[5];
    const float* v1  = (const float*)d_in[6];
    const float* a1  = (const float*)d_in[7];
    const float* wp  = (const float*)d_in[8];
    const float* bp  = (const float*)d_in[9];
    const float* g2  = (const float*)d_in[10];
    const float* be2 = (const float*)d_in[11];
    const float* m2  = (const float*)d_in[12];
    const float* v2  = (const float*)d_in[13];
    const float* a2  = (const float*)d_in[14];

    float* Qws   = (float*)d_ws;                            // 8,388,608 f = 33.6 MB
    float* Mfull = Qws   + (size_t)Bv * Fv * Tv * DCv;      //   524,288 f =  2.1 MB
    float* W1T   = Mfull + (size_t)512 * 1024;              //     2,048 f
    float* B1f   = W1T   + 2048;                            //        32 f
    float* W2f   = B1f   + 32;                              //     2,048 f
    float* B2f   = W2f   + 2048;                            //        64 f

    kprep<<<dim3(1), dim3(512), 0, stream>>>(
        w1, b1, g1, be1, m1, v1, wp, bp, g2, be2, m2, v2, W1T, B1f, W2f, B2f);
    kc1_conv<<<dim3(Bv * Fv * 4), dim3(256), 0, stream>>>(inp, W1T, B1f, a1, Qws);
    km_build<<<dim3(Bv * Fv), dim3(256), 0, stream>>>(Qws, Mfull);
    kf_fused<<<dim3(Bv * Fv), dim3(512), 0, stream>>>(
        inp, Qws, Mfull, W2f, B2f, a2, (float*)d_out);
}

// Round 17
// 90.939 us; speedup vs baseline: 1.4160x; 1.0331x over previous
//
#include <hip/hip_runtime.h>
#include <math.h>

#define Bv  4
#define Cv  64
#define DCv 32
#define Fv  128
#define Tv  512
#define FT  (Fv * 512)

// ---------------------------------------------------------------------------
// KPREP: fold BN into weights. W1T[k][c] (transposed, for kc1), B1f;
// W2f[o][k] (row-major, for kf), B2f.
// ---------------------------------------------------------------------------
__global__ __launch_bounds__(512)
void kprep(const float* __restrict__ w1, const float* __restrict__ b1,
           const float* __restrict__ g1, const float* __restrict__ be1,
           const float* __restrict__ m1, const float* __restrict__ v1,
           const float* __restrict__ wp, const float* __restrict__ bp,
           const float* __restrict__ g2, const float* __restrict__ be2,
           const float* __restrict__ m2, const float* __restrict__ v2,
           float* __restrict__ W1T, float* __restrict__ B1f,
           float* __restrict__ W2f, float* __restrict__ B2f)
{
    const int tid = threadIdx.x;
    #pragma unroll
    for (int i = 0; i < 4; ++i) {
        const int e = tid * 4 + i;          // W1T: e = k*32 + c
        const int c = e & 31, k = e >> 5;
        W1T[e] = w1[c * Cv + k] * (g1[c] * rsqrtf(v1[c] + 1e-5f));
    }
    {
        const int o = tid >> 3;             // 8 float4 per 32-wide row
        const float s = g2[o] * rsqrtf(v2[o] + 1e-5f);
        float4 v = *(const float4*)&wp[tid * 4];
        v.x *= s; v.y *= s; v.z *= s; v.w *= s;
        *(float4*)&W2f[tid * 4] = v;
    }
    if (tid < DCv) {
        const float s = g1[tid] * rsqrtf(v1[tid] + 1e-5f);
        B1f[tid] = (b1[tid] - m1[tid]) * s + be1[tid];
    }
    if (tid < Cv) {
        const float s = g2[tid] * rsqrtf(v2[tid] + 1e-5f);
        B2f[tid] = (bp[tid] - m2[tid]) * s + be2[tid];
    }
}

// ---------------------------------------------------------------------------
// KC1: conv1, 8-row x 4-t register tile. grid (bf, t-half) = 1024 x 256
// (4 waves). Wave w = 64-t chunk; lane: tl = l&15 (4 t), cl = l>>4 (8-row
// group, 4 groups = all 32 rows). Per k: 1 global b128 (feeds 32 FMA) +
// 2 broadcast LDS b128. Live set acc[32]+x+a ~ 50 regs -> fits the 64-VGPR
// budget of (256,4) (r14's (256,8)/32-VGPR spill avoided).
// ---------------------------------------------------------------------------
__global__ __launch_bounds__(256, 4)
void kc1_conv(const float* __restrict__ inp,
              const float* __restrict__ W1T, const float* __restrict__ B1f,
              const float* __restrict__ a1,
              float* __restrict__ Qws)
{
    __shared__ __align__(16) float sW[Cv * DCv];   // 8 KB [k][c]
    __shared__ float sB[DCv];

    const int tid = threadIdx.x;
    const int bid = blockIdx.x;
    const int h   = bid & 1;
    const int bf  = bid >> 1;
    const int b   = bf >> 7;
    const int f   = bf & 127;

    {
        const int e = tid * 8;
        *(float4*)&sW[e]     = *(const float4*)&W1T[e];
        *(float4*)&sW[e + 4] = *(const float4*)&W1T[e + 4];
    }
    if (tid < DCv) sB[tid] = B1f[tid];
    const float alpha1 = a1[0];
    __syncthreads();

    const int w  = tid >> 6, l = tid & 63;
    const int tl = l & 15, cl = l >> 4;
    const int r0 = cl * 8;
    const int t0 = h * 256 + w * 64 + tl * 4;

    const float* px = inp + (size_t)(b * Cv) * FT + f * 512 + t0;

    float acc[32];
    #pragma unroll
    for (int i = 0; i < 32; ++i) acc[i] = 0.f;

    #pragma unroll 8
    for (int k = 0; k < Cv; ++k) {
        const float4 x   = *(const float4*)&px[(size_t)k * FT];
        const float4 a0  = *(const float4*)&sW[k * DCv + r0];
        const float4 a1v = *(const float4*)&sW[k * DCv + r0 + 4];
        acc[0*4+0] = fmaf(a0.x, x.x, acc[0*4+0]); acc[0*4+1] = fmaf(a0.x, x.y, acc[0*4+1]);
        acc[0*4+2] = fmaf(a0.x, x.z, acc[0*4+2]); acc[0*4+3] = fmaf(a0.x, x.w, acc[0*4+3]);
        acc[1*4+0] = fmaf(a0.y, x.x, acc[1*4+0]); acc[1*4+1] = fmaf(a0.y, x.y, acc[1*4+1]);
        acc[1*4+2] = fmaf(a0.y, x.z, acc[1*4+2]); acc[1*4+3] = fmaf(a0.y, x.w, acc[1*4+3]);
        acc[2*4+0] = fmaf(a0.z, x.x, acc[2*4+0]); acc[2*4+1] = fmaf(a0.z, x.y, acc[2*4+1]);
        acc[2*4+2] = fmaf(a0.z, x.z, acc[2*4+2]); acc[2*4+3] = fmaf(a0.z, x.w, acc[2*4+3]);
        acc[3*4+0] = fmaf(a0.w, x.x, acc[3*4+0]); acc[3*4+1] = fmaf(a0.w, x.y, acc[3*4+1]);
        acc[3*4+2] = fmaf(a0.w, x.z, acc[3*4+2]); acc[3*4+3] = fmaf(a0.w, x.w, acc[3*4+3]);
        acc[4*4+0] = fmaf(a1v.x, x.x, acc[4*4+0]); acc[4*4+1] = fmaf(a1v.x, x.y, acc[4*4+1]);
        acc[4*4+2] = fmaf(a1v.x, x.z, acc[4*4+2]); acc[4*4+3] = fmaf(a1v.x, x.w, acc[4*4+3]);
        acc[5*4+0] = fmaf(a1v.y, x.x, acc[5*4+0]); acc[5*4+1] = fmaf(a1v.y, x.y, acc[5*4+1]);
        acc[5*4+2] = fmaf(a1v.y, x.z, acc[5*4+2]); acc[5*4+3] = fmaf(a1v.y, x.w, acc[5*4+3]);
        acc[6*4+0] = fmaf(a1v.z, x.x, acc[6*4+0]); acc[6*4+1] = fmaf(a1v.z, x.y, acc[6*4+1]);
        acc[6*4+2] = fmaf(a1v.z, x.z, acc[6*4+2]); acc[6*4+3] = fmaf(a1v.z, x.w, acc[6*4+3]);
        acc[7*4+0] = fmaf(a1v.w, x.x, acc[7*4+0]); acc[7*4+1] = fmaf(a1v.w, x.y, acc[7*4+1]);
        acc[7*4+2] = fmaf(a1v.w, x.z, acc[7*4+2]); acc[7*4+3] = fmaf(a1v.w, x.w, acc[7*4+3]);
    }

    const float b0 = sB[r0+0], b1_ = sB[r0+1], b2 = sB[r0+2], b3 = sB[r0+3];
    const float b4 = sB[r0+4], b5  = sB[r0+5], b6 = sB[r0+6], b7 = sB[r0+7];
    #pragma unroll
    for (int j = 0; j < 4; ++j) {
        float z0 = acc[0*4+j] + b0, z1 = acc[1*4+j] + b1_;
        float z2 = acc[2*4+j] + b2, z3 = acc[3*4+j] + b3;
        float z4 = acc[4*4+j] + b4, z5 = acc[5*4+j] + b5;
        float z6 = acc[6*4+j] + b6, z7 = acc[7*4+j] + b7;
        z0 = z0 >= 0.f ? z0 : alpha1 * z0;  z1 = z1 >= 0.f ? z1 : alpha1 * z1;
        z2 = z2 >= 0.f ? z2 : alpha1 * z2;  z3 = z3 >= 0.f ? z3 : alpha1 * z3;
        z4 = z4 >= 0.f ? z4 : alpha1 * z4;  z5 = z5 >= 0.f ? z5 : alpha1 * z5;
        z6 = z6 >= 0.f ? z6 : alpha1 * z6;  z7 = z7 >= 0.f ? z7 : alpha1 * z7;
        float4 v0; v0.x = z0; v0.y = z1; v0.z = z2; v0.w = z3;
        float4 v1; v1.x = z4; v1.y = z5; v1.z = z6; v1.w = z7;
        float* qg = Qws + ((size_t)bf * Tv + t0 + j) * DCv + r0;
        *(float4*)&qg[0] = v0;
        *(float4*)&qg[4] = v1;
    }
}

// ---------------------------------------------------------------------------
// KM: M = Q Q^T / sqrt(32). One block per bf. Proven (~9 us, 60 TF).
// ---------------------------------------------------------------------------
__global__ __launch_bounds__(256)
void km_build(const float* __restrict__ Qws, float* __restrict__ Mfull)
{
    __shared__ __align__(16) float sP[4][1024];  // 16 KB

    const int tid   = threadIdx.x;
    const int bf    = blockIdx.x;
    const int slice = tid >> 6;
    const int l     = tid & 63;
    const int c1b   = l >> 3;
    const int c2b   = l & 7;

    const float* qp = Qws + ((size_t)bf * Tv + slice * 128) * DCv;
    float4 r0 = {0,0,0,0}, r1 = {0,0,0,0}, r2 = {0,0,0,0}, r3 = {0,0,0,0};
    #pragma unroll 4
    for (int i = 0; i < 128; ++i) {
        const float4 qa = *(const float4*)&qp[i * 32 + c1b * 4];
        const float4 qb = *(const float4*)&qp[i * 32 + c2b * 4];
        r0.x = fmaf(qa.x, qb.x, r0.x); r0.y = fmaf(qa.x, qb.y, r0.y);
        r0.z = fmaf(qa.x, qb.z, r0.z); r0.w = fmaf(qa.x, qb.w, r0.w);
        r1.x = fmaf(qa.y, qb.x, r1.x); r1.y = fmaf(qa.y, qb.y, r1.y);
        r1.z = fmaf(qa.y, qb.z, r1.z); r1.w = fmaf(qa.y, qb.w, r1.w);
        r2.x = fmaf(qa.z, qb.x, r2.x); r2.y = fmaf(qa.z, qb.y, r2.y);
        r2.z = fmaf(qa.z, qb.z, r2.z); r2.w = fmaf(qa.z, qb.w, r2.w);
        r3.x = fmaf(qa.w, qb.x, r3.x); r3.y = fmaf(qa.w, qb.y, r3.y);
        r3.z = fmaf(qa.w, qb.z, r3.z); r3.w = fmaf(qa.w, qb.w, r3.w);
    }
    *(float4*)&sP[slice][(c1b * 4 + 0) * DCv + c2b * 4] = r0;
    *(float4*)&sP[slice][(c1b * 4 + 1) * DCv + c2b * 4] = r1;
    *(float4*)&sP[slice][(c1b * 4 + 2) * DCv + c2b * 4] = r2;
    *(float4*)&sP[slice][(c1b * 4 + 3) * DCv + c2b * 4] = r3;
    __syncthreads();

    const float INV = 0.17677669529663687f;  // 1/sqrt(32)
    float4 v0 = *(const float4*)&sP[0][tid * 4];
    float4 v1 = *(const float4*)&sP[1][tid * 4];
    float4 v2 = *(const float4*)&sP[2][tid * 4];
    float4 v3 = *(const float4*)&sP[3][tid * 4];
    float4 o;
    o.x = ((v0.x + v1.x) + (v2.x + v3.x)) * INV;
    o.y = ((v0.y + v1.y) + (v2.y + v3.y)) * INV;
    o.z = ((v0.z + v1.z) + (v2.z + v3.z)) * INV;
    o.w = ((v0.w + v1.w) + (v2.w + v3.w)) * INV;
    *(float4*)&Mfull[(size_t)bf * 1024 + tid * 4] = o;
}

// ---------------------------------------------------------------------------
// KF: fused O=M*Q -> mask -> softmax -> P -> OUT=W2f*P+B2f -> PReLU ->
// +residual. Unchanged from r16 (measured 46-48 us).
// ---------------------------------------------------------------------------
#define GEMM_CC(ACC, cc, a)                                       \
    ACC[(cc)*4+0] = fmaf(a.x, x0.x, ACC[(cc)*4+0]);               \
    ACC[(cc)*4+0] = fmaf(a.y, x1.x, ACC[(cc)*4+0]);               \
    ACC[(cc)*4+0] = fmaf(a.z, x2.x, ACC[(cc)*4+0]);               \
    ACC[(cc)*4+0] = fmaf(a.w, x3.x, ACC[(cc)*4+0]);               \
    ACC[(cc)*4+1] = fmaf(a.x, x0.y, ACC[(cc)*4+1]);               \
    ACC[(cc)*4+1] = fmaf(a.y, x1.y, ACC[(cc)*4+1]);               \
    ACC[(cc)*4+1] = fmaf(a.z, x2.y, ACC[(cc)*4+1]);               \
    ACC[(cc)*4+1] = fmaf(a.w, x3.y, ACC[(cc)*4+1]);               \
    ACC[(cc)*4+2] = fmaf(a.x, x0.z, ACC[(cc)*4+2]);               \
    ACC[(cc)*4+2] = fmaf(a.y, x1.z, ACC[(cc)*4+2]);               \
    ACC[(cc)*4+2] = fmaf(a.z, x2.z, ACC[(cc)*4+2]);               \
    ACC[(cc)*4+2] = fmaf(a.w, x3.z, ACC[(cc)*4+2]);               \
    ACC[(cc)*4+3] = fmaf(a.x, x0.w, ACC[(cc)*4+3]);               \
    ACC[(cc)*4+3] = fmaf(a.y, x1.w, ACC[(cc)*4+3]);               \
    ACC[(cc)*4+3] = fmaf(a.z, x2.w, ACC[(cc)*4+3]);               \
    ACC[(cc)*4+3] = fmaf(a.w, x3.w, ACC[(cc)*4+3]);

__global__ __launch_bounds__(512, 2)
void kf_fused(const float* __restrict__ inp,
              const float* __restrict__ Qws, const float* __restrict__ Mfull,
              const float* __restrict__ W2f, const float* __restrict__ B2f,
              const float* __restrict__ a2,
              float* __restrict__ out)
{
    __shared__ __align__(16) float sX[DCv * Tv];   // 64 KB [k][t]: Q, then P
    __shared__ __align__(16) float sM[DCv * 36];   // 4.5 KB
    __shared__ __align__(16) float sW[Cv * 36];    // 9 KB
    __shared__ float sPart[8][DCv];
    __shared__ float sMx[DCv], sRZ[DCv];
    __shared__ float sB2[Cv];

    const int tid = threadIdx.x;
    const int bf  = blockIdx.x;
    const int b   = bf >> 7;
    const int f   = bf & 127;
    const int w   = tid >> 6;
    const int l   = tid & 63;
    const int tl  = l & 15;
    const int cl  = l >> 4;
    const int t0  = w * 64 + tl * 4;          // this lane's 4 t-columns
    const int limit = f + (Tv - Fv + 1);      // valid iff t < limit (385..512)
    const float alpha2 = a2[0];

    // ---- stage: q column, M, W2f, B2f ----
    const float* qg = Qws + ((size_t)bf * Tv + tid) * DCv;
    float4 q0 = *(const float4*)&qg[0],  q1 = *(const float4*)&qg[4];
    float4 q2 = *(const float4*)&qg[8],  q3 = *(const float4*)&qg[12];
    float4 q4 = *(const float4*)&qg[16], q5 = *(const float4*)&qg[20];
    float4 q6 = *(const float4*)&qg[24], q7 = *(const float4*)&qg[28];

    if (tid < 256) {
        const int c = tid >> 3, k0 = (tid & 7) << 2;
        float4 v = *(const float4*)&Mfull[(size_t)bf * 1024 + tid * 4];
        *(float4*)&sM[c * 36 + k0] = v;
    }
    {
        const int c = tid >> 3, k0 = (tid & 7) << 2;
        float4 v = *(const float4*)&W2f[tid * 4];
        *(float4*)&sW[c * 36 + k0] = v;
    }
    if (tid < Cv) sB2[tid] = B2f[tid];

    {
        const int t = tid;
        sX[ 0*Tv+t]=q0.x; sX[ 1*Tv+t]=q0.y; sX[ 2*Tv+t]=q0.z; sX[ 3*Tv+t]=q0.w;
        sX[ 4*Tv+t]=q1.x; sX[ 5*Tv+t]=q1.y; sX[ 6*Tv+t]=q1.z; sX[ 7*Tv+t]=q1.w;
        sX[ 8*Tv+t]=q2.x; sX[ 9*Tv+t]=q2.y; sX[10*Tv+t]=q2.z; sX[11*Tv+t]=q2.w;
        sX[12*Tv+t]=q3.x; sX[13*Tv+t]=q3.y; sX[14*Tv+t]=q3.z; sX[15*Tv+t]=q3.w;
        sX[16*Tv+t]=q4.x; sX[17*Tv+t]=q4.y; sX[18*Tv+t]=q4.z; sX[19*Tv+t]=q4.w;
        sX[20*Tv+t]=q5.x; sX[21*Tv+t]=q5.y; sX[22*Tv+t]=q5.z; sX[23*Tv+t]=q5.w;
        sX[24*Tv+t]=q6.x; sX[25*Tv+t]=q6.y; sX[26*Tv+t]=q6.z; sX[27*Tv+t]=q6.w;
        sX[28*Tv+t]=q7.x; sX[29*Tv+t]=q7.y; sX[30*Tv+t]=q7.z; sX[31*Tv+t]=q7.w;
    }
    __syncthreads();

    // ---- GEMM1: O[32c][t], two 4-row tiles SHARING x-reads ----
    float oA[16], oB[16];
    #pragma unroll
    for (int i = 0; i < 16; ++i) { oA[i] = 0.f; oB[i] = 0.f; }
    const int cA = cl * 4;
    const int cB = 16 + cl * 4;
    #pragma unroll
    for (int k0 = 0; k0 < 32; k0 += 4) {
        const float4 x0 = *(const float4*)&sX[(k0+0)*Tv + t0];
        const float4 x1 = *(const float4*)&sX[(k0+1)*Tv + t0];
        const float4 x2 = *(const float4*)&sX[(k0+2)*Tv + t0];
        const float4 x3 = *(const float4*)&sX[(k0+3)*Tv + t0];
        { const float4 a = *(const float4*)&sM[(cA+0)*36 + k0]; GEMM_CC(oA,0,a) }
        { const float4 a = *(const float4*)&sM[(cA+1)*36 + k0]; GEMM_CC(oA,1,a) }
        { const float4 a = *(const float4*)&sM[(cA+2)*36 + k0]; GEMM_CC(oA,2,a) }
        { const float4 a = *(const float4*)&sM[(cA+3)*36 + k0]; GEMM_CC(oA,3,a) }
        { const float4 a = *(const float4*)&sM[(cB+0)*36 + k0]; GEMM_CC(oB,0,a) }
        { const float4 a = *(const float4*)&sM[(cB+1)*36 + k0]; GEMM_CC(oB,1,a) }
        { const float4 a = *(const float4*)&sM[(cB+2)*36 + k0]; GEMM_CC(oB,2,a) }
        { const float4 a = *(const float4*)&sM[(cB+3)*36 + k0]; GEMM_CC(oB,3,a) }
    }

    // ---- mask ----
    #pragma unroll
    for (int jt = 0; jt < 4; ++jt) {
        if (t0 + jt >= limit) {
            #pragma unroll
            for (int cc = 0; cc < 4; ++cc) { oA[cc*4+jt] = -INFINITY; oB[cc*4+jt] = -INFINITY; }
        }
    }

    // ---- stats pass 1: per-(wave,c) max ----
    #pragma unroll
    for (int cc = 0; cc < 4; ++cc) {
        float mA = fmaxf(fmaxf(oA[cc*4+0], oA[cc*4+1]), fmaxf(oA[cc*4+2], oA[cc*4+3]));
        float mB = fmaxf(fmaxf(oB[cc*4+0], oB[cc*4+1]), fmaxf(oB[cc*4+2], oB[cc*4+3]));
        #pragma unroll
        for (int s = 1; s < 16; s <<= 1) {
            mA = fmaxf(mA, __shfl_xor(mA, s));
            mB = fmaxf(mB, __shfl_xor(mB, s));
        }
        if (tl == 0) { sPart[w][cA + cc] = mA; sPart[w][cB + cc] = mB; }
    }
    __syncthreads();
    if (tid < DCv) {
        float m = sPart[0][tid];
        #pragma unroll
        for (int ww = 1; ww < 8; ++ww) m = fmaxf(m, sPart[ww][tid]);
        sMx[tid] = m;
    }
    __syncthreads();

    // ---- exp + pass 2: per-(wave,c) sum ----
    #pragma unroll
    for (int cc = 0; cc < 4; ++cc) {
        const float mxA = sMx[cA + cc], mxB = sMx[cB + cc];
        float sA = 0.f, sB = 0.f;
        #pragma unroll
        for (int jt = 0; jt < 4; ++jt) {
            oA[cc*4+jt] = __expf(oA[cc*4+jt] - mxA); sA += oA[cc*4+jt];
            oB[cc*4+jt] = __expf(oB[cc*4+jt] - mxB); sB += oB[cc*4+jt];
        }
        #pragma unroll
        for (int s = 1; s < 16; s <<= 1) {
            sA += __shfl_xor(sA, s);
            sB += __shfl_xor(sB, s);
        }
        if (tl == 0) { sPart[w][cA + cc] = sA; sPart[w][cB + cc] = sB; }
    }
    __syncthreads();
    if (tid < DCv) {
        float z = 0.f;
        #pragma unroll
        for (int ww = 0; ww < 8; ++ww) z += sPart[ww][tid];
        sRZ[tid] = 1.f / z;
    }
    __syncthreads();

    // ---- P = e * rz -> overwrite sX ----
    #pragma unroll
    for (int cc = 0; cc < 4; ++cc) {
        const float rA = sRZ[cA + cc], rB = sRZ[cB + cc];
        float4 pA, pB;
        pA.x = oA[cc*4+0]*rA; pA.y = oA[cc*4+1]*rA; pA.z = oA[cc*4+2]*rA; pA.w = oA[cc*4+3]*rA;
        pB.x = oB[cc*4+0]*rB; pB.y = oB[cc*4+1]*rB; pB.z = oB[cc*4+2]*rB; pB.w = oB[cc*4+3]*rB;
        *(float4*)&sX[(cA + cc)*Tv + t0] = pA;
        *(float4*)&sX[(cB + cc)*Tv + t0] = pB;
    }
    __syncthreads();

    // ---- GEMM2: OUT[64oc][t] in TWO 8-row-tile iterations (x-reads shared) ----
    #pragma unroll 1
    for (int it = 0; it < 2; ++it) {
        const int oc0 = it * 32 + cl * 8;

        float acc[32];
        #pragma unroll
        for (int i = 0; i < 32; ++i) acc[i] = 0.f;

        #pragma unroll
        for (int k0 = 0; k0 < 32; k0 += 4) {
            const float4 x0 = *(const float4*)&sX[(k0+0)*Tv + t0];
            const float4 x1 = *(const float4*)&sX[(k0+1)*Tv + t0];
            const float4 x2 = *(const float4*)&sX[(k0+2)*Tv + t0];
            const float4 x3 = *(const float4*)&sX[(k0+3)*Tv + t0];
            { const float4 a = *(const float4*)&sW[(oc0+0)*36 + k0]; GEMM_CC(acc,0,a) }
            { const float4 a = *(const float4*)&sW[(oc0+1)*36 + k0]; GEMM_CC(acc,1,a) }
            { const float4 a = *(const float4*)&sW[(oc0+2)*36 + k0]; GEMM_CC(acc,2,a) }
            { const float4 a = *(const float4*)&sW[(oc0+3)*36 + k0]; GEMM_CC(acc,3,a) }
            { const float4 a = *(const float4*)&sW[(oc0+4)*36 + k0]; GEMM_CC(acc,4,a) }
            { const float4 a = *(const float4*)&sW[(oc0+5)*36 + k0]; GEMM_CC(acc,5,a) }
            { const float4 a = *(const float4*)&sW[(oc0+6)*36 + k0]; GEMM_CC(acc,6,a) }
            { const float4 a = *(const float4*)&sW[(oc0+7)*36 + k0]; GEMM_CC(acc,7,a) }
        }

        const float* rp = inp + ((size_t)(b * Cv + oc0) * Fv + f) * Tv + t0;
        float*       po = out + ((size_t)(b * Cv + oc0) * Fv + f) * Tv + t0;
        #pragma unroll
        for (int r = 0; r < 8; ++r) {
            const float4 rv = *(const float4*)&rp[(size_t)r * FT];
            const float bb = sB2[oc0 + r];
            float z0 = acc[r*4+0] + bb, z1 = acc[r*4+1] + bb;
            float z2 = acc[r*4+2] + bb, z3 = acc[r*4+3] + bb;
            z0 = z0 >= 0.f ? z0 : alpha2 * z0;
            z1 = z1 >= 0.f ? z1 : alpha2 * z1;
            z2 = z2 >= 0.f ? z2 : alpha2 * z2;
            z3 = z3 >= 0.f ? z3 : alpha2 * z3;
            float4 o4; o4.x = z0 + rv.x; o4.y = z1 + rv.y;
            o4.z = z2 + rv.z; o4.w = z3 + rv.w;
            *(float4*)&po[(size_t)r * FT] = o4;
        }
    }
}

extern "C" void kernel_launch(void* const* d_in, const int* in_sizes, int n_in,
                              void* d_out, int out_size, void* d_ws, size_t ws_size,
                              hipStream_t stream) {
    const float* inp = (const float*)d_in[0];
    const float* w1  = (const float*)d_in[1];
    const float* b1  = (const float*)d_in[2];
    const float* g1  = (const float*)d_in[3];
    const float* be1 = (const float*)d_in[4];
    const float* m1  = (const float*)d_in[5];
    const float* v1  = (const float*)d_in[6];
    const float* a1  = (const float*)d_in[7];
    const float* wp  = (const float*)d_in[8];
    const float* bp  = (const float*)d_in[9];
    const float* g2  = (const float*)d_in[10];
    const float* be2 = (const float*)d_in[11];
    const float* m2  = (const float*)d_in[12];
    const float* v2  = (const float*)d_in[13];
    const float* a2  = (const float*)d_in[14];

    float* Qws   = (float*)d_ws;                            // 8,388,608 f = 33.6 MB
    float* Mfull = Qws   + (size_t)Bv * Fv * Tv * DCv;      //   524,288 f =  2.1 MB
    float* W1T   = Mfull + (size_t)512 * 1024;              //     2,048 f
    float* B1f   = W1T   + 2048;                            //        32 f
    float* W2f   = B1f   + 32;                              //     2,048 f
    float* B2f   = W2f   + 2048;                            //        64 f

    kprep<<<dim3(1), dim3(512), 0, stream>>>(
        w1, b1, g1, be1, m1, v1, wp, bp, g2, be2, m2, v2, W1T, B1f, W2f, B2f);
    kc1_conv<<<dim3(Bv * Fv * 2), dim3(256), 0, stream>>>(inp, W1T, B1f, a1, Qws);
    km_build<<<dim3(Bv * Fv), dim3(256), 0, stream>>>(Qws, Mfull);
    kf_fused<<<dim3(Bv * Fv), dim3(512), 0, stream>>>(
        inp, Qws, Mfull, W2f, B2f, a2, (float*)d_out);
}